// Round 8
// baseline (3484.256 us; speedup 1.0000x reference)
//
#include <hip/hip_runtime.h>
#include <stdint.h>

#define V_ 32000
#define E_ 512
#define H_ 1024
#define M_ 256
#define B_ 2
#define S_ 1024
#define GC_ 24

typedef unsigned short u16;
typedef unsigned int u32;
typedef unsigned long long u64;

typedef __attribute__((ext_vector_type(8))) short short8;
typedef __attribute__((ext_vector_type(4))) float floatx4;
typedef __attribute__((ext_vector_type(2))) float floatx2;
typedef __attribute__((ext_vector_type(2))) _Float16 halfx2;

__device__ __forceinline__ float bf2f(u16 u){ return __uint_as_float(((u32)u) << 16); }
__device__ __forceinline__ float bflo(u32 u){ return __uint_as_float(u << 16); }
__device__ __forceinline__ float bfhi(u32 u){ return __uint_as_float(u & 0xffff0000u); }
__device__ __forceinline__ u16 f2bf(float f){
  u32 u = __float_as_uint(f);
  u32 r = (u + 0x7fffu + ((u >> 16) & 1u)) >> 16;
  return (u16)r;
}
__device__ __forceinline__ float sigm(float x){ return 1.f / (1.f + __expf(-x)); }

// 2-wide f16 dot product accumulating into f32 (v_dot2_f32_f16); graceful fallback.
__device__ __forceinline__ float dot2f16(u32 a, u32 b, float c){
#if __has_builtin(__builtin_amdgcn_fdot2)
  return __builtin_amdgcn_fdot2(__builtin_bit_cast(halfx2, a),
                                __builtin_bit_cast(halfx2, b), c, false);
#else
  halfx2 av = __builtin_bit_cast(halfx2, a);
  halfx2 bv = __builtin_bit_cast(halfx2, b);
  return fmaf((float)av.y, (float)bv.y, fmaf((float)av.x, (float)bv.x, c));
#endif
}

// ---------------- dtype probe: low-u16-as-bf16 plausibility test on emb ----------------
__global__ __launch_bounds__(64) void detect_kernel(const u32* __restrict__ emb,
    int* __restrict__ flag, float* __restrict__ scal,
    const void* __restrict__ lam, const void* __restrict__ ms)
{
  int lane = threadIdx.x;
  int c = 0;
  for (int i = lane; i < 256; i += 64){
    u32 w = emb[i];
    float a = fabsf(__uint_as_float((w & 0xffffu) << 16));
    if (a > 1e-5f && a < 1.0f) c++;
  }
  #pragma unroll
  for (int o = 32; o; o >>= 1) c += __shfl_down(c, o, 64);
  if (lane == 0){
    int isf32 = (c < 128) ? 1 : 0;
    *flag = isf32;
    if (isf32) scal[0] = ((const float*)lam)[0];
    else {
      float v = bf2f(((const u16*)lam)[0]);
      scal[0] = (fabsf(v) <= 4.0f) ? v : ((const float*)lam)[0];
    }
    if (isf32) scal[1] = ((const float*)ms)[0];
    else {
      u16 a = ((const u16*)ms)[0];
      float v = bf2f(a);
      scal[1] = (a != 0 && fabsf(v) > 1e-4f && fabsf(v) < 1e4f) ? v : ((const float*)ms)[0];
    }
  }
}

// ---------------- canonicalize any float input to bf16 ----------------
__global__ __launch_bounds__(256) void conv_kernel(const void* __restrict__ src,
    u16* __restrict__ dst, int n, const int* __restrict__ flag)
{
  int i = blockIdx.x * 256 + threadIdx.x;
  if (i >= n) return;
  if (*flag) dst[i] = f2bf(((const float*)src)[i]);
  else       dst[i] = ((const u16*)src)[i];
}

// ---------------- canonicalize to f16 (for GRU W_hh: used by v_dot2_f32_f16) ----------------
__global__ __launch_bounds__(256) void convh_kernel(const void* __restrict__ src,
    u16* __restrict__ dst, int n, const int* __restrict__ flag)
{
  int i = blockIdx.x * 256 + threadIdx.x;
  if (i >= n) return;
  float v = (*flag) ? ((const float*)src)[i] : bf2f(((const u16*)src)[i]);
  _Float16 h = (_Float16)v;
  dst[i] = __builtin_bit_cast(u16, h);
}

// ---------------- smear: x' = emb[ids]; x'[t] += lam*sigmoid(x[t,:24]@smW)*x[t-1] ----------------
__global__ __launch_bounds__(64) void smear_kernel(const int* __restrict__ ids,
    const u16* __restrict__ emb, const u16* __restrict__ smW,
    const float* __restrict__ scal, u16* __restrict__ xs)
{
  int row = blockIdx.x;                 // b*S + t
  int t = row & (S_ - 1);
  int lane = threadIdx.x;
  int id = ids[row];
  const u16* er = emb + (size_t)id * E_;
  float sg = 0.f;
  if (t > 0){
    float p = 0.f;
    if (lane < GC_) p = bf2f(er[lane]) * bf2f(smW[lane]);
    #pragma unroll
    for (int o = 32; o; o >>= 1) p += __shfl_down(p, o, 64);
    float dot = __shfl(p, 0, 64);
    sg = scal[0] * sigm(dot);
  }
  uint4 cur = ((const uint4*)er)[lane];
  uint4 outv = cur;
  if (t > 0){
    const u16* ep = emb + (size_t)ids[row - 1] * E_;
    uint4 prv = ((const uint4*)ep)[lane];
    const u16* cu = (const u16*)&cur;
    const u16* pu = (const u16*)&prv;
    u16* po = (u16*)&outv;
    #pragma unroll
    for (int j = 0; j < 8; j++) po[j] = f2bf(bf2f(cu[j]) + sg * bf2f(pu[j]));
  }
  ((uint4*)(xs + (size_t)row * E_))[lane] = outv;
}

// ---------------- generic MFMA GEMM: C(M,N) = A(M,K) * Bm(N,K)^T + bias(N) ----------------
template<bool OUT_BF16>
__global__ __launch_bounds__(256) void gemm_bt(
    const u16* __restrict__ A, const u16* __restrict__ Bm,
    const u16* __restrict__ bias, void* __restrict__ Cout,
    int K, int Ndim)
{
  int wave = threadIdx.x >> 6, lane = threadIdx.x & 63;
  int wm = wave >> 1, wn = wave & 1;
  int m0 = blockIdx.y * 128 + wm * 64;
  int n0 = blockIdx.x * 128 + wn * 64;
  int lrow = lane & 15, lq = lane >> 4;
  floatx4 acc[4][4];
  #pragma unroll
  for (int i = 0; i < 4; i++)
    #pragma unroll
    for (int j = 0; j < 4; j++) acc[i][j] = (floatx4)0.f;
  const u16* Ab = A + (size_t)(m0 + lrow) * K + lq * 8;
  const u16* Bb = Bm + (size_t)(n0 + lrow) * K + lq * 8;
  for (int k0 = 0; k0 < K; k0 += 32){
    short8 af[4], bfr[4];
    #pragma unroll
    for (int tt = 0; tt < 4; tt++)
      af[tt] = *(const short8*)(Ab + (size_t)tt * 16 * K + k0);
    #pragma unroll
    for (int tt = 0; tt < 4; tt++)
      bfr[tt] = *(const short8*)(Bb + (size_t)tt * 16 * K + k0);
    #pragma unroll
    for (int im = 0; im < 4; im++)
      #pragma unroll
      for (int in = 0; in < 4; in++)
        acc[im][in] = __builtin_amdgcn_mfma_f32_16x16x32_bf16(af[im], bfr[in], acc[im][in], 0, 0, 0);
  }
  #pragma unroll
  for (int in = 0; in < 4; in++){
    int n = n0 + in * 16 + lrow;
    float bv = bf2f(bias[n]);
    #pragma unroll
    for (int im = 0; im < 4; im++){
      int mb = m0 + im * 16 + lq * 4;
      #pragma unroll
      for (int r = 0; r < 4; r++){
        float v = acc[im][in][r] + bv;
        size_t off = (size_t)(mb + r) * Ndim + n;
        if (OUT_BF16) ((u16*)Cout)[off] = f2bf(v);
        else          ((float*)Cout)[off] = v;
      }
    }
  }
}

// ---------------- GRU persistent scan: 64 WGs x 1024 thr, direct-poll v9 ----------------
// v9 = v8 (direct-poll, 1 barrier/step, parity red, in-register pack, single-wave
// tail with early publish) with a lower-contention pipelined poll front-end:
//  - 16 LOADER LANES per wave (l<16), each covering 4 slots via 2 u64 agent atomic
//    loads -> 256 polling threads/WG (was 1024), 4x fewer poll streams chip-wide.
//  - 2-deep software-pipelined spin: two load pairs in flight; check the older pair
//    while the newer is in flight -> discovery gap ~RTT/2 (was ~RTT).
//  - pack: loader lane m holds f16 pairs 2m (from a0) and 2m+1 (from b0);
//    consumer lane fetches its 16 pairs via 16 shfls (same count as v8).
//  All tags/publish/tail/red logic bit-identical to the passing v8.
__global__ __launch_bounds__(1024) void gru_kernel(
    const float* __restrict__ xg, const u16* __restrict__ W_hh,
    const u16* __restrict__ b_hh, u32* __restrict__ hslot,
    u16* __restrict__ states)
{
  const int b = blockIdx.x >> 5;
  const int ibase = (blockIdx.x & 31) * 32;
  const int tid = threadIdx.x;
  const int w = tid >> 6;          // wave id [0,16): k-range [64w, 64w+64)
  const int l = tid & 63;
  const int kg = tid >> 5;         // k-chunk [0,32) (32 k each)
  const int il = l & 31;
  const int i = ibase + il;        // output this thread contributes to

  __shared__ float red[2][3][16][32];   // parity-double-buffered partials

  // resident weights: 3 gates x 32 k f16 for (output i, k-chunk kg)
  uint4 Wv[3][4];
  #pragma unroll
  for (int g = 0; g < 3; g++){
    const uint4* p = (const uint4*)(W_hh + ((size_t)(g * H_ + i)) * H_ + kg * 32);
    #pragma unroll
    for (int q = 0; q < 4; q++) Wv[g][q] = p[q];
  }

  // tail-only state (wave 0, lanes 0-31): h_old, biases, xg(t) in registers
  float ho = 0.f, xr0 = 0.f, xz0 = 0.f, xn0 = 0.f, bh0 = 0.f, bh1 = 0.f, bh2 = 0.f;
  if (tid < 32){
    bh0 = bf2f(b_hh[ibase + tid]);
    bh1 = bf2f(b_hh[H_ + ibase + tid]);
    bh2 = bf2f(b_hh[2 * H_ + ibase + tid]);
    size_t base = ((size_t)(b * S_)) * 3072 + ibase + tid;
    xr0 = xg[base]; xz0 = xg[base + 1024]; xn0 = xg[base + 2048];
  }

  const bool ldr = (l < 16);
  const int m = l & 15;                 // loader lane id: slots 4m..4m+3 of wave's 64
  const int sbase = (l & 32) ? 8 : 0;   // shfl source base for this half's pairs

  for (int t = 0; t < S_; t++){
    const int p = t & 1;
    const u32 want = (u32)t;
    // ---- pipelined poll: 16 loader lanes, 2 u64 pairs, 2 iterations in flight ----
    const u32* s32 = hslot + (size_t)(p ^ 1) * B_ * H_ + (size_t)b * H_ + 64 * w + 4 * m;
    const u64* rp = (const u64*)s32;
    u64 a0 = 0, b0 = 0, a1 = 0, b1 = 0;
    if (ldr){
      a0 = __hip_atomic_load(rp,     __ATOMIC_RELAXED, __HIP_MEMORY_SCOPE_AGENT);
      b0 = __hip_atomic_load(rp + 1, __ATOMIC_RELAXED, __HIP_MEMORY_SCOPE_AGENT);
      a1 = __hip_atomic_load(rp,     __ATOMIC_RELAXED, __HIP_MEMORY_SCOPE_AGENT);
      b1 = __hip_atomic_load(rp + 1, __ATOMIC_RELAXED, __HIP_MEMORY_SCOPE_AGENT);
    }
    for (;;){
      bool ok = true;
      if (ldr)
        ok = (((u32)(a0 >> 16) & 0xffffu) == want) & (((u32)(a0 >> 48)) == want) &
             (((u32)(b0 >> 16) & 0xffffu) == want) & (((u32)(b0 >> 48)) == want);
      if (__all(ok)) break;
      a0 = a1; b0 = b1;
      if (ldr){
        a1 = __hip_atomic_load(rp,     __ATOMIC_RELAXED, __HIP_MEMORY_SCOPE_AGENT);
        b1 = __hip_atomic_load(rp + 1, __ATOMIC_RELAXED, __HIP_MEMORY_SCOPE_AGENT);
      }
    }
    // ---- pack: loader lane m -> pair 2m (pA), pair 2m+1 (pB); f16x2 words ----
    u32 pA = ((u32)a0 & 0xffffu) | ((((u32)(a0 >> 32)) & 0xffffu) << 16);
    u32 pB = ((u32)b0 & 0xffffu) | ((((u32)(b0 >> 32)) & 0xffffu) << 16);
    // consumer lane needs pairs sbase*2 + q (q=0..15): src lane = sbase + (q>>1), reg = q&1
    u32 h2[16];
    #pragma unroll
    for (int q = 0; q < 16; q++)
      h2[q] = (u32)__shfl((int)((q & 1) ? pB : pA), sbase + (q >> 1), 64);
    // ---- matvec partials: 48 dot2 over this thread's 32-k chunk ----
    float pr = 0.f, pz = 0.f, pn = 0.f;
    #pragma unroll
    for (int q = 0; q < 4; q++){
      uint4 wr = Wv[0][q], wz = Wv[1][q], wn4 = Wv[2][q];
      pr = dot2f16(wr.x, h2[q*4+0], pr);  pz = dot2f16(wz.x, h2[q*4+0], pz);  pn = dot2f16(wn4.x, h2[q*4+0], pn);
      pr = dot2f16(wr.y, h2[q*4+1], pr);  pz = dot2f16(wz.y, h2[q*4+1], pz);  pn = dot2f16(wn4.y, h2[q*4+1], pn);
      pr = dot2f16(wr.z, h2[q*4+2], pr);  pz = dot2f16(wz.z, h2[q*4+2], pz);  pn = dot2f16(wn4.z, h2[q*4+2], pn);
      pr = dot2f16(wr.w, h2[q*4+3], pr);  pz = dot2f16(wz.w, h2[q*4+3], pz);  pn = dot2f16(wn4.w, h2[q*4+3], pn);
    }
    // combine the wave's two 32-k chunks
    pr += __shfl_xor(pr, 32, 64);
    pz += __shfl_xor(pz, 32, 64);
    pn += __shfl_xor(pn, 32, 64);
    if (l < 32){
      red[p][0][w][il] = pr;
      red[p][1][w][il] = pz;
      red[p][2][w][il] = pn;
    }
    __syncthreads();
    // ---- tail: wave 0 lanes 0-31 finalize + single coalesced publish ----
    if (tid < 32){
      __builtin_amdgcn_s_setprio(1);
      float hr = 0.f, hz = 0.f, hn = 0.f;
      #pragma unroll
      for (int ww = 0; ww < 16; ww++){
        hr += red[p][0][ww][tid];
        hz += red[p][1][ww][tid];
        hn += red[p][2][ww][tid];
      }
      float r = sigm(xr0 + hr + bh0);
      float z = sigm(xz0 + hz + bh1);
      float xx = xn0 + r * (hn + bh2);
      float ax = fabsf(xx);
      float et = __expf(-2.f * ax);                     // overflow-safe fast tanh
      float n = copysignf((1.f - et) * __builtin_amdgcn_rcpf(1.f + et), xx);
      float hnew = (1.f - z) * n + z * ho;
      ho = hnew;
      u16 h16 = __builtin_bit_cast(u16, (_Float16)hnew);
      u32 tgv = (((u32)(t + 1)) << 16) | (u32)h16;
      __hip_atomic_store(&hslot[((size_t)(p * B_ + b)) * H_ + ibase + tid], tgv,
                         __ATOMIC_RELAXED, __HIP_MEMORY_SCOPE_AGENT);
      states[((size_t)(b * S_ + t)) * H_ + ibase + tid] = f2bf(hnew);
      __builtin_amdgcn_s_setprio(0);
      if (t + 1 < S_){
        size_t base = ((size_t)(b * S_ + t + 1)) * 3072 + ibase + tid;
        xr0 = xg[base]; xz0 = xg[base + 1024]; xn0 = xg[base + 2048];
      }
    }
  }
}

// ---------------- g gate: sigmoid(states @ Wg + bg) ----------------
__global__ __launch_bounds__(256) void gk_kernel(const u16* __restrict__ states,
    const u16* __restrict__ Wg, const u16* __restrict__ bg, float* __restrict__ gws)
{
  int row = blockIdx.x * 4 + (threadIdx.x >> 6);
  int lane = threadIdx.x & 63;
  const u16* sr = states + (size_t)row * H_;
  float p = 0.f;
  #pragma unroll
  for (int j = 0; j < 16; j++){
    int c = j * 64 + lane;
    p += bf2f(sr[c]) * bf2f(Wg[c]);
  }
  #pragma unroll
  for (int o = 32; o; o >>= 1) p += __shfl_xor(p, o, 64);
  if (lane == 0) gws[row] = sigm(p + bf2f(bg[0]));
}

// ---------------- bitonic sort of (id<<11 | t) per batch ----------------
__global__ __launch_bounds__(1024) void sort_kernel(const int* __restrict__ ids, int* __restrict__ sorted)
{
  int b = blockIdx.x, tid = threadIdx.x;
  __shared__ int arr[S_];
  arr[tid] = (ids[b * S_ + tid] << 11) | tid;
  __syncthreads();
  for (int k = 2; k <= S_; k <<= 1){
    for (int j = k >> 1; j > 0; j >>= 1){
      int ixj = tid ^ j;
      if (ixj > tid){
        int a = arr[tid], c = arr[ixj];
        bool dir = (tid & k) == 0;
        if (dir ? (a > c) : (a < c)){ arr[tid] = c; arr[ixj] = a; }
      }
      __syncthreads();
    }
  }
  sorted[b * S_ + tid] = arr[tid];
}

// ---------------- attention: scores -> masked softmax -> gated = attn * g * mscale ----------------
__global__ __launch_bounds__(256) void attn_kernel(
    const u16* __restrict__ q, const u16* __restrict__ k,
    const float* __restrict__ gws, const float* __restrict__ scal,
    float* __restrict__ gated)
{
  int s = blockIdx.x, b = blockIdx.y;
  if (s == 0) return;
  int tid = threadIdx.x;
  __shared__ float qs[M_];
  __shared__ float rbm[4], rbs[4];
  if (tid < M_) qs[tid] = bf2f(q[((size_t)(b * S_ + s)) * M_ + tid]);
  __syncthreads();
  float myS[4];
  float lmax = -1e30f;
  #pragma unroll
  for (int r = 0; r < 4; r++){
    int t = tid + 256 * r;
    if (t < s){
      const uint4* kr = (const uint4*)(k + ((size_t)(b * S_ + t)) * M_);
      float d = 0.f;
      #pragma unroll
      for (int j = 0; j < 32; j++){
        uint4 kv = kr[j];
        u32 cc[4] = {kv.x, kv.y, kv.z, kv.w};
        #pragma unroll
        for (int e = 0; e < 4; e++)
          d += bflo(cc[e]) * qs[j * 8 + e * 2] + bfhi(cc[e]) * qs[j * 8 + e * 2 + 1];
      }
      d *= 0.0625f;                  // 1/sqrt(256)
      myS[r] = d;
      lmax = fmaxf(lmax, d);
    }
  }
  #pragma unroll
  for (int o = 32; o; o >>= 1) lmax = fmaxf(lmax, __shfl_xor(lmax, o, 64));
  if ((tid & 63) == 0) rbm[tid >> 6] = lmax;
  __syncthreads();
  float gmax = fmaxf(fmaxf(rbm[0], rbm[1]), fmaxf(rbm[2], rbm[3]));
  float lsum = 0.f;
  #pragma unroll
  for (int r = 0; r < 4; r++){
    int t = tid + 256 * r;
    if (t < s){ myS[r] = __expf(myS[r] - gmax); lsum += myS[r]; }
  }
  #pragma unroll
  for (int o = 32; o; o >>= 1) lsum += __shfl_xor(lsum, o, 64);
  if ((tid & 63) == 0) rbs[tid >> 6] = lsum;
  __syncthreads();
  float gsum = rbs[0] + rbs[1] + rbs[2] + rbs[3];
  float fac = gws[b * S_ + s] * scal[1] / gsum;
  float* grow = gated + ((size_t)(b * S_ + s)) * S_;
  #pragma unroll
  for (int r = 0; r < 4; r++){
    int t = tid + 256 * r;
    if (t < s) grow[t] = myS[r] * fac;
  }
}

// ---------------- scatter: out[b,s,ids[b,t]] += gated[b,s,t] (dup-merged, race-free, fp32) ----------------
__global__ __launch_bounds__(256) void scatter_kernel(
    const int* __restrict__ sorted, const float* __restrict__ gated,
    float* __restrict__ out)
{
  int gid = blockIdx.x * 256 + threadIdx.x;
  int e = gid & (S_ - 1);
  int row = gid >> 10;                  // b*S + s
  int s = row & (S_ - 1);
  int b = row >> 10;
  const int* sb = sorted + b * S_;
  int pk = sb[e];
  int v = pk >> 11;
  if (e > 0 && (sb[e - 1] >> 11) == v) return;   // only leaders
  const float* grow = gated + (size_t)row * S_;
  float sum = 0.f; bool any = false;
  for (int j = e; j < S_; j++){
    int pj = sb[j];
    if ((pj >> 11) != v) break;
    int t = pj & 2047;
    if (t < s){ sum += grow[t]; any = true; }
  }
  if (any){
    size_t off = (size_t)row * V_ + v;
    out[off] += sum;
  }
}

extern "C" void kernel_launch(void* const* d_in, const int* in_sizes, int n_in,
                              void* d_out, int out_size, void* d_ws, size_t ws_size,
                              hipStream_t stream)
{
  const int*  ids   = (const int*)d_in[0];
  const void* emb   = d_in[1];
  const void* W_ih  = d_in[2];
  const void* W_hh  = d_in[3];
  const void* b_ih  = d_in[4];
  const void* b_hh  = d_in[5];
  const void* Wq    = d_in[6];
  const void* bq    = d_in[7];
  const void* Wk    = d_in[8];
  const void* bk    = d_in[9];
  const void* Wg    = d_in[10];
  const void* bg    = d_in[11];
  const void* Whe   = d_in[12];
  const void* bhe   = d_in[13];
  const void* obias = d_in[14];
  const void* ms    = d_in[15];
  const void* smW   = d_in[16];
  const void* lam   = d_in[17];
  (void)in_sizes; (void)n_in; (void)out_size; (void)ws_size;

  char* ws = (char*)d_ws;
  int*   flag   = (int*)(ws + 0);
  float* scal   = (float*)(ws + 256);
  u32*   hslot  = (u32*)(ws + 512);        // [2][B][H] tagged-f16 u32 slots (16 KB)
  u16*   c_emb  = (u16*)(ws + 33280);
  u16*   c_Wih  = (u16*)(ws + 32801280);
  u16*   c_Whh  = (u16*)(ws + 35947008);   // f16 content (GRU dot2 path)
  u16*   c_Wq   = (u16*)(ws + 42238464);
  u16*   c_Wk   = (u16*)(ws + 42762752);
  u16*   c_Wg   = (u16*)(ws + 43287040);
  u16*   c_Whe  = (u16*)(ws + 43289088);
  u16*   c_bih  = (u16*)(ws + 44337664);
  u16*   c_bhh  = (u16*)(ws + 44343808);
  u16*   c_bq   = (u16*)(ws + 44349952);
  u16*   c_bk   = (u16*)(ws + 44350464);
  u16*   c_bg   = (u16*)(ws + 44350976);
  u16*   c_bhe  = (u16*)(ws + 44351232);
  u16*   c_ob   = (u16*)(ws + 44352256);
  u16*   c_smW  = (u16*)(ws + 44416512);
  u16*   xs     = (u16*)(ws + 44416768);
  float* xg     = (float*)(ws + 46513920);
  u16*   states = (u16*)(ws + 71679744);
  u16*   hs     = (u16*)(ws + 75874048);
  u16*   qb     = (u16*)(ws + 77971200);
  u16*   kb     = (u16*)(ws + 79019776);
  float* gws    = (float*)(ws + 80068352);
  float* gated  = (float*)(ws + 80076544);
  int*   sorted = (int*)(ws + 88465152);
  float* out = (float*)d_out;

  hipMemsetAsync(hslot, 0, 16384, stream);   // h0 = 0 with tag 0
  detect_kernel<<<dim3(1), dim3(64), 0, stream>>>((const u32*)emb, flag, scal, lam, ms);

  #define CONV(src, dst, n) conv_kernel<<<dim3(((n)+255)/256), dim3(256), 0, stream>>>(src, dst, n, flag)
  CONV(emb,   c_emb, V_ * E_);
  CONV(W_ih,  c_Wih, 3 * H_ * E_);
  convh_kernel<<<dim3((3 * H_ * H_ + 255) / 256), dim3(256), 0, stream>>>(W_hh, c_Whh, 3 * H_ * H_, flag);
  CONV(Wq,    c_Wq,  M_ * H_);
  CONV(Wk,    c_Wk,  M_ * H_);
  CONV(Wg,    c_Wg,  H_);
  CONV(Whe,   c_Whe, E_ * H_);
  CONV(b_ih,  c_bih, 3 * H_);
  CONV(b_hh,  c_bhh, 3 * H_);
  CONV(bq,    c_bq,  M_);
  CONV(bk,    c_bk,  M_);
  CONV(bg,    c_bg,  1);
  CONV(bhe,   c_bhe, E_);
  CONV(obias, c_ob,  V_);
  CONV(smW,   c_smW, GC_);
  #undef CONV

  smear_kernel<<<dim3(B_ * S_), dim3(64), 0, stream>>>(ids, c_emb, c_smW, scal, xs);
  gemm_bt<false><<<dim3(3072 / 128, 2048 / 128), dim3(256), 0, stream>>>(xs, c_Wih, c_bih, (void*)xg, E_, 3072);
  gru_kernel<<<dim3(64), dim3(1024), 0, stream>>>(xg, c_Whh, c_bhh, hslot, states);
  gemm_bt<true><<<dim3(512 / 128, 16), dim3(256), 0, stream>>>(states, c_Whe, c_bhe, (void*)hs, H_, 512);
  gemm_bt<true><<<dim3(256 / 128, 16), dim3(256), 0, stream>>>(states, c_Wq, c_bq, (void*)qb, H_, 256);
  gemm_bt<true><<<dim3(256 / 128, 16), dim3(256), 0, stream>>>(states, c_Wk, c_bk, (void*)kb, H_, 256);
  gk_kernel<<<dim3(512), dim3(256), 0, stream>>>(states, c_Wg, c_bg, gws);
  sort_kernel<<<dim3(B_), dim3(1024), 0, stream>>>(ids, sorted);
  attn_kernel<<<dim3(S_, B_), dim3(256), 0, stream>>>(qb, kb, gws, scal, gated);
  gemm_bt<false><<<dim3(V_ / 128, 16), dim3(256), 0, stream>>>(hs, c_emb, c_ob, (void*)out, E_, V_);
  scatter_kernel<<<dim3(B_ * S_ * S_ / 256), dim3(256), 0, stream>>>(sorted, gated, out);
}

// Round 9
// 2674.332 us; speedup vs baseline: 1.3029x; 1.3029x over previous
//
#include <hip/hip_runtime.h>
#include <stdint.h>

#define V_ 32000
#define E_ 512
#define H_ 1024
#define M_ 256
#define B_ 2
#define S_ 1024
#define GC_ 24

typedef unsigned short u16;
typedef unsigned int u32;
typedef unsigned long long u64;

typedef __attribute__((ext_vector_type(8))) short short8;
typedef __attribute__((ext_vector_type(4))) float floatx4;
typedef __attribute__((ext_vector_type(2))) float floatx2;
typedef __attribute__((ext_vector_type(2))) _Float16 halfx2;

__device__ __forceinline__ float bf2f(u16 u){ return __uint_as_float(((u32)u) << 16); }
__device__ __forceinline__ float bflo(u32 u){ return __uint_as_float(u << 16); }
__device__ __forceinline__ float bfhi(u32 u){ return __uint_as_float(u & 0xffff0000u); }
__device__ __forceinline__ u16 f2bf(float f){
  u32 u = __float_as_uint(f);
  u32 r = (u + 0x7fffu + ((u >> 16) & 1u)) >> 16;
  return (u16)r;
}
__device__ __forceinline__ float sigm(float x){ return 1.f / (1.f + __expf(-x)); }

// 2-wide f16 dot product accumulating into f32 (v_dot2_f32_f16); graceful fallback.
__device__ __forceinline__ float dot2f16(u32 a, u32 b, float c){
#if __has_builtin(__builtin_amdgcn_fdot2)
  return __builtin_amdgcn_fdot2(__builtin_bit_cast(halfx2, a),
                                __builtin_bit_cast(halfx2, b), c, false);
#else
  halfx2 av = __builtin_bit_cast(halfx2, a);
  halfx2 bv = __builtin_bit_cast(halfx2, b);
  return fmaf((float)av.y, (float)bv.y, fmaf((float)av.x, (float)bv.x, c));
#endif
}

// ---------------- dtype probe: low-u16-as-bf16 plausibility test on emb ----------------
__global__ __launch_bounds__(64) void detect_kernel(const u32* __restrict__ emb,
    int* __restrict__ flag, float* __restrict__ scal,
    const void* __restrict__ lam, const void* __restrict__ ms)
{
  int lane = threadIdx.x;
  int c = 0;
  for (int i = lane; i < 256; i += 64){
    u32 w = emb[i];
    float a = fabsf(__uint_as_float((w & 0xffffu) << 16));
    if (a > 1e-5f && a < 1.0f) c++;
  }
  #pragma unroll
  for (int o = 32; o; o >>= 1) c += __shfl_down(c, o, 64);
  if (lane == 0){
    int isf32 = (c < 128) ? 1 : 0;
    *flag = isf32;
    if (isf32) scal[0] = ((const float*)lam)[0];
    else {
      float v = bf2f(((const u16*)lam)[0]);
      scal[0] = (fabsf(v) <= 4.0f) ? v : ((const float*)lam)[0];
    }
    if (isf32) scal[1] = ((const float*)ms)[0];
    else {
      u16 a = ((const u16*)ms)[0];
      float v = bf2f(a);
      scal[1] = (a != 0 && fabsf(v) > 1e-4f && fabsf(v) < 1e4f) ? v : ((const float*)ms)[0];
    }
  }
}

// ---------------- canonicalize any float input to bf16 ----------------
__global__ __launch_bounds__(256) void conv_kernel(const void* __restrict__ src,
    u16* __restrict__ dst, int n, const int* __restrict__ flag)
{
  int i = blockIdx.x * 256 + threadIdx.x;
  if (i >= n) return;
  if (*flag) dst[i] = f2bf(((const float*)src)[i]);
  else       dst[i] = ((const u16*)src)[i];
}

// ---------------- canonicalize to f16 (for GRU W_hh: used by v_dot2_f32_f16) ----------------
__global__ __launch_bounds__(256) void convh_kernel(const void* __restrict__ src,
    u16* __restrict__ dst, int n, const int* __restrict__ flag)
{
  int i = blockIdx.x * 256 + threadIdx.x;
  if (i >= n) return;
  float v = (*flag) ? ((const float*)src)[i] : bf2f(((const u16*)src)[i]);
  _Float16 h = (_Float16)v;
  dst[i] = __builtin_bit_cast(u16, h);
}

// ---------------- smear: x' = emb[ids]; x'[t] += lam*sigmoid(x[t,:24]@smW)*x[t-1] ----------------
__global__ __launch_bounds__(64) void smear_kernel(const int* __restrict__ ids,
    const u16* __restrict__ emb, const u16* __restrict__ smW,
    const float* __restrict__ scal, u16* __restrict__ xs)
{
  int row = blockIdx.x;                 // b*S + t
  int t = row & (S_ - 1);
  int lane = threadIdx.x;
  int id = ids[row];
  const u16* er = emb + (size_t)id * E_;
  float sg = 0.f;
  if (t > 0){
    float p = 0.f;
    if (lane < GC_) p = bf2f(er[lane]) * bf2f(smW[lane]);
    #pragma unroll
    for (int o = 32; o; o >>= 1) p += __shfl_down(p, o, 64);
    float dot = __shfl(p, 0, 64);
    sg = scal[0] * sigm(dot);
  }
  uint4 cur = ((const uint4*)er)[lane];
  uint4 outv = cur;
  if (t > 0){
    const u16* ep = emb + (size_t)ids[row - 1] * E_;
    uint4 prv = ((const uint4*)ep)[lane];
    const u16* cu = (const u16*)&cur;
    const u16* pu = (const u16*)&prv;
    u16* po = (u16*)&outv;
    #pragma unroll
    for (int j = 0; j < 8; j++) po[j] = f2bf(bf2f(cu[j]) + sg * bf2f(pu[j]));
  }
  ((uint4*)(xs + (size_t)row * E_))[lane] = outv;
}

// ---------------- generic MFMA GEMM: C(M,N) = A(M,K) * Bm(N,K)^T + bias(N) ----------------
template<bool OUT_BF16>
__global__ __launch_bounds__(256) void gemm_bt(
    const u16* __restrict__ A, const u16* __restrict__ Bm,
    const u16* __restrict__ bias, void* __restrict__ Cout,
    int K, int Ndim)
{
  int wave = threadIdx.x >> 6, lane = threadIdx.x & 63;
  int wm = wave >> 1, wn = wave & 1;
  int m0 = blockIdx.y * 128 + wm * 64;
  int n0 = blockIdx.x * 128 + wn * 64;
  int lrow = lane & 15, lq = lane >> 4;
  floatx4 acc[4][4];
  #pragma unroll
  for (int i = 0; i < 4; i++)
    #pragma unroll
    for (int j = 0; j < 4; j++) acc[i][j] = (floatx4)0.f;
  const u16* Ab = A + (size_t)(m0 + lrow) * K + lq * 8;
  const u16* Bb = Bm + (size_t)(n0 + lrow) * K + lq * 8;
  for (int k0 = 0; k0 < K; k0 += 32){
    short8 af[4], bfr[4];
    #pragma unroll
    for (int tt = 0; tt < 4; tt++)
      af[tt] = *(const short8*)(Ab + (size_t)tt * 16 * K + k0);
    #pragma unroll
    for (int tt = 0; tt < 4; tt++)
      bfr[tt] = *(const short8*)(Bb + (size_t)tt * 16 * K + k0);
    #pragma unroll
    for (int im = 0; im < 4; im++)
      #pragma unroll
      for (int in = 0; in < 4; in++)
        acc[im][in] = __builtin_amdgcn_mfma_f32_16x16x32_bf16(af[im], bfr[in], acc[im][in], 0, 0, 0);
  }
  #pragma unroll
  for (int in = 0; in < 4; in++){
    int n = n0 + in * 16 + lrow;
    float bv = bf2f(bias[n]);
    #pragma unroll
    for (int im = 0; im < 4; im++){
      int mb = m0 + im * 16 + lq * 4;
      #pragma unroll
      for (int r = 0; r < 4; r++){
        float v = acc[im][in][r] + bv;
        size_t off = (size_t)(mb + r) * Ndim + n;
        if (OUT_BF16) ((u16*)Cout)[off] = f2bf(v);
        else          ((float*)Cout)[off] = v;
      }
    }
  }
}

// ---------------- GRU persistent scan: 64 WGs x 1024 thr (v10 = v2 + micro-deltas) ----------------
// Skeleton identical to the session-best v2 (1948us): waves 0-7 poll (512 lanes,
// one u64 each), stage packed f16 pairs to LDS, TWO barriers/step, broadcast
// conflict-free compute reads, cross-wave red[] + single-wave tail.
// Proven-safe grafts only:
//  (a) tagged-f16 u32 slots ((t+1)<<16 | f16(h)) [v5/v8-proven]: poller's u64
//      covers 2 slots; poll footprint 8KB->4KB/step; publish 256B->128B.
//  (b) register tail [v8-proven]: biases, h_old, xg(t) in wave-0 registers
//      (xg prefetched a step ahead) -> lds_xg and f32 lds_h deleted; staging
//      writes drop to one u32 per poller.
//  (c) tail publishes BEFORE states-write/xg-prefetch, setprio-wrapped.
// Sync proof unchanged from v2 (re-derived for u32 format; see round notes).
__global__ __launch_bounds__(1024) void gru_kernel(
    const float* __restrict__ xg, const u16* __restrict__ W_hh,
    const u16* __restrict__ b_hh, u32* __restrict__ hslot,
    u16* __restrict__ states)
{
  const int b = blockIdx.x >> 5;
  const int ibase = (blockIdx.x & 31) * 32;
  const int tid = threadIdx.x;
  const int kg = tid >> 5;     // 32-k chunk [0,32); uniform per half-wave
  const int il = tid & 31;
  const int i = ibase + il;    // output this thread contributes to
  const int w = tid >> 6;      // wave id [0,16)

  __shared__ u32   lds_hpk[2][H_ / 2];  // packed f16 pairs of h (parity-dbuf)
  __shared__ float red[3][16][32];      // cross-wave partials (barrier-protected)

  // resident weights: 3 gates x 32 k f16 for (output i, k-chunk kg)
  uint4 Wv[3][4];
  #pragma unroll
  for (int g = 0; g < 3; g++){
    const uint4* p = (const uint4*)(W_hh + ((size_t)(g * H_ + i)) * H_ + kg * 32);
    #pragma unroll
    for (int q = 0; q < 4; q++) Wv[g][q] = p[q];
  }

  // tail-only state (wave 0, lanes 0-31): h_old, biases, xg(t) in registers
  float ho = 0.f, xr0 = 0.f, xz0 = 0.f, xn0 = 0.f, bh0 = 0.f, bh1 = 0.f, bh2 = 0.f;
  if (tid < 32){
    bh0 = bf2f(b_hh[ibase + tid]);
    bh1 = bf2f(b_hh[H_ + ibase + tid]);
    bh2 = bf2f(b_hh[2 * H_ + ibase + tid]);
    size_t base = ((size_t)(b * S_)) * 3072 + ibase + tid;
    xr0 = xg[base]; xz0 = xg[base + 1024]; xn0 = xg[base + 2048];
  }

  for (int t = 0; t < S_; t++){
    const int p = t & 1;
    // ---- poll + stage: 512 lanes, one u64 (2 tagged-u32 slots) each ----
    if (tid < 512){
      const u64* rp = (const u64*)(hslot + ((size_t)((p ^ 1) * B_ + b)) * H_) + tid;
      const u32 tg = (u32)t;
      u64 u0;
      do {
        u0 = __hip_atomic_load(rp, __ATOMIC_RELAXED, __HIP_MEMORY_SCOPE_AGENT);
      } while ((((u32)(u0 >> 16) & 0xffffu) != tg) | (((u32)(u0 >> 48)) != tg));
      lds_hpk[p][tid] = ((u32)u0 & 0xffffu) | (((u32)(u0 >> 32)) << 16);
    }
    __syncthreads();
    // ---- matvec partials: 48 dot2 over this thread's 32-k chunk (broadcast reads) ----
    const u32* hp = &lds_hpk[p][kg * 16];
    float pr = 0.f, pz = 0.f, pn = 0.f;
    #pragma unroll
    for (int q = 0; q < 4; q++){
      uint4 wr = Wv[0][q], wz = Wv[1][q], wn4 = Wv[2][q];
      u32 cr[4] = {wr.x, wr.y, wr.z, wr.w};
      u32 cz[4] = {wz.x, wz.y, wz.z, wz.w};
      u32 cn[4] = {wn4.x, wn4.y, wn4.z, wn4.w};
      #pragma unroll
      for (int e = 0; e < 4; e++){
        u32 h2 = hp[q * 4 + e];
        pr = dot2f16(cr[e], h2, pr);
        pz = dot2f16(cz[e], h2, pz);
        pn = dot2f16(cn[e], h2, pn);
      }
    }
    // combine the wave's two 32-k chunks, write per-wave partials
    pr += __shfl_xor(pr, 32, 64);
    pz += __shfl_xor(pz, 32, 64);
    pn += __shfl_xor(pn, 32, 64);
    if ((tid & 63) < 32){
      red[0][w][il] = pr; red[1][w][il] = pz; red[2][w][il] = pn;
    }
    __syncthreads();
    // ---- tail: wave 0 lanes 0-31 finalize; publish FIRST, then states/prefetch ----
    if (tid < 32){
      __builtin_amdgcn_s_setprio(1);
      float hr = 0.f, hz = 0.f, hn = 0.f;
      #pragma unroll
      for (int ww = 0; ww < 16; ww++){
        hr += red[0][ww][tid]; hz += red[1][ww][tid]; hn += red[2][ww][tid];
      }
      float r = sigm(xr0 + hr + bh0);
      float z = sigm(xz0 + hz + bh1);
      float xx = xn0 + r * (hn + bh2);
      float ax = fabsf(xx);
      float et = __expf(-2.f * ax);                     // overflow-safe fast tanh
      float n = copysignf((1.f - et) * __builtin_amdgcn_rcpf(1.f + et), xx);
      float hnew = (1.f - z) * n + z * ho;
      ho = hnew;
      u16 h16 = __builtin_bit_cast(u16, (_Float16)hnew);
      u32 tgv = (((u32)(t + 1)) << 16) | (u32)h16;
      __hip_atomic_store(&hslot[((size_t)(p * B_ + b)) * H_ + ibase + tid], tgv,
                         __ATOMIC_RELAXED, __HIP_MEMORY_SCOPE_AGENT);
      __builtin_amdgcn_s_setprio(0);
      states[((size_t)(b * S_ + t)) * H_ + ibase + tid] = f2bf(hnew);
      if (t + 1 < S_){
        size_t base = ((size_t)(b * S_ + t + 1)) * 3072 + ibase + tid;
        xr0 = xg[base]; xz0 = xg[base + 1024]; xn0 = xg[base + 2048];
      }
    }
  }
}

// ---------------- g gate: sigmoid(states @ Wg + bg) ----------------
__global__ __launch_bounds__(256) void gk_kernel(const u16* __restrict__ states,
    const u16* __restrict__ Wg, const u16* __restrict__ bg, float* __restrict__ gws)
{
  int row = blockIdx.x * 4 + (threadIdx.x >> 6);
  int lane = threadIdx.x & 63;
  const u16* sr = states + (size_t)row * H_;
  float p = 0.f;
  #pragma unroll
  for (int j = 0; j < 16; j++){
    int c = j * 64 + lane;
    p += bf2f(sr[c]) * bf2f(Wg[c]);
  }
  #pragma unroll
  for (int o = 32; o; o >>= 1) p += __shfl_xor(p, o, 64);
  if (lane == 0) gws[row] = sigm(p + bf2f(bg[0]));
}

// ---------------- bitonic sort of (id<<11 | t) per batch ----------------
__global__ __launch_bounds__(1024) void sort_kernel(const int* __restrict__ ids, int* __restrict__ sorted)
{
  int b = blockIdx.x, tid = threadIdx.x;
  __shared__ int arr[S_];
  arr[tid] = (ids[b * S_ + tid] << 11) | tid;
  __syncthreads();
  for (int k = 2; k <= S_; k <<= 1){
    for (int j = k >> 1; j > 0; j >>= 1){
      int ixj = tid ^ j;
      if (ixj > tid){
        int a = arr[tid], c = arr[ixj];
        bool dir = (tid & k) == 0;
        if (dir ? (a > c) : (a < c)){ arr[tid] = c; arr[ixj] = a; }
      }
      __syncthreads();
    }
  }
  sorted[b * S_ + tid] = arr[tid];
}

// ---------------- attention: scores -> masked softmax -> gated = attn * g * mscale ----------------
__global__ __launch_bounds__(256) void attn_kernel(
    const u16* __restrict__ q, const u16* __restrict__ k,
    const float* __restrict__ gws, const float* __restrict__ scal,
    float* __restrict__ gated)
{
  int s = blockIdx.x, b = blockIdx.y;
  if (s == 0) return;
  int tid = threadIdx.x;
  __shared__ float qs[M_];
  __shared__ float rbm[4], rbs[4];
  if (tid < M_) qs[tid] = bf2f(q[((size_t)(b * S_ + s)) * M_ + tid]);
  __syncthreads();
  float myS[4];
  float lmax = -1e30f;
  #pragma unroll
  for (int r = 0; r < 4; r++){
    int t = tid + 256 * r;
    if (t < s){
      const uint4* kr = (const uint4*)(k + ((size_t)(b * S_ + t)) * M_);
      float d = 0.f;
      #pragma unroll
      for (int j = 0; j < 32; j++){
        uint4 kv = kr[j];
        u32 cc[4] = {kv.x, kv.y, kv.z, kv.w};
        #pragma unroll
        for (int e = 0; e < 4; e++)
          d += bflo(cc[e]) * qs[j * 8 + e * 2] + bfhi(cc[e]) * qs[j * 8 + e * 2 + 1];
      }
      d *= 0.0625f;                  // 1/sqrt(256)
      myS[r] = d;
      lmax = fmaxf(lmax, d);
    }
  }
  #pragma unroll
  for (int o = 32; o; o >>= 1) lmax = fmaxf(lmax, __shfl_xor(lmax, o, 64));
  if ((tid & 63) == 0) rbm[tid >> 6] = lmax;
  __syncthreads();
  float gmax = fmaxf(fmaxf(rbm[0], rbm[1]), fmaxf(rbm[2], rbm[3]));
  float lsum = 0.f;
  #pragma unroll
  for (int r = 0; r < 4; r++){
    int t = tid + 256 * r;
    if (t < s){ myS[r] = __expf(myS[r] - gmax); lsum += myS[r]; }
  }
  #pragma unroll
  for (int o = 32; o; o >>= 1) lsum += __shfl_xor(lsum, o, 64);
  if ((tid & 63) == 0) rbs[tid >> 6] = lsum;
  __syncthreads();
  float gsum = rbs[0] + rbs[1] + rbs[2] + rbs[3];
  float fac = gws[b * S_ + s] * scal[1] / gsum;
  float* grow = gated + ((size_t)(b * S_ + s)) * S_;
  #pragma unroll
  for (int r = 0; r < 4; r++){
    int t = tid + 256 * r;
    if (t < s) grow[t] = myS[r] * fac;
  }
}

// ---------------- scatter: out[b,s,ids[b,t]] += gated[b,s,t] (dup-merged, race-free, fp32) ----------------
__global__ __launch_bounds__(256) void scatter_kernel(
    const int* __restrict__ sorted, const float* __restrict__ gated,
    float* __restrict__ out)
{
  int gid = blockIdx.x * 256 + threadIdx.x;
  int e = gid & (S_ - 1);
  int row = gid >> 10;                  // b*S + s
  int s = row & (S_ - 1);
  int b = row >> 10;
  const int* sb = sorted + b * S_;
  int pk = sb[e];
  int v = pk >> 11;
  if (e > 0 && (sb[e - 1] >> 11) == v) return;   // only leaders
  const float* grow = gated + (size_t)row * S_;
  float sum = 0.f; bool any = false;
  for (int j = e; j < S_; j++){
    int pj = sb[j];
    if ((pj >> 11) != v) break;
    int t = pj & 2047;
    if (t < s){ sum += grow[t]; any = true; }
  }
  if (any){
    size_t off = (size_t)row * V_ + v;
    out[off] += sum;
  }
}

extern "C" void kernel_launch(void* const* d_in, const int* in_sizes, int n_in,
                              void* d_out, int out_size, void* d_ws, size_t ws_size,
                              hipStream_t stream)
{
  const int*  ids   = (const int*)d_in[0];
  const void* emb   = d_in[1];
  const void* W_ih  = d_in[2];
  const void* W_hh  = d_in[3];
  const void* b_ih  = d_in[4];
  const void* b_hh  = d_in[5];
  const void* Wq    = d_in[6];
  const void* bq    = d_in[7];
  const void* Wk    = d_in[8];
  const void* bk    = d_in[9];
  const void* Wg    = d_in[10];
  const void* bg    = d_in[11];
  const void* Whe   = d_in[12];
  const void* bhe   = d_in[13];
  const void* obias = d_in[14];
  const void* ms    = d_in[15];
  const void* smW   = d_in[16];
  const void* lam   = d_in[17];
  (void)in_sizes; (void)n_in; (void)out_size; (void)ws_size;

  char* ws = (char*)d_ws;
  int*   flag   = (int*)(ws + 0);
  float* scal   = (float*)(ws + 256);
  u32*   hslot  = (u32*)(ws + 512);        // [2][B][H] tagged-f16 u32 slots (16 KB)
  u16*   c_emb  = (u16*)(ws + 33280);
  u16*   c_Wih  = (u16*)(ws + 32801280);
  u16*   c_Whh  = (u16*)(ws + 35947008);   // f16 content (GRU dot2 path)
  u16*   c_Wq   = (u16*)(ws + 42238464);
  u16*   c_Wk   = (u16*)(ws + 42762752);
  u16*   c_Wg   = (u16*)(ws + 43287040);
  u16*   c_Whe  = (u16*)(ws + 43289088);
  u16*   c_bih  = (u16*)(ws + 44337664);
  u16*   c_bhh  = (u16*)(ws + 44343808);
  u16*   c_bq   = (u16*)(ws + 44349952);
  u16*   c_bk   = (u16*)(ws + 44350464);
  u16*   c_bg   = (u16*)(ws + 44350976);
  u16*   c_bhe  = (u16*)(ws + 44351232);
  u16*   c_ob   = (u16*)(ws + 44352256);
  u16*   c_smW  = (u16*)(ws + 44416512);
  u16*   xs     = (u16*)(ws + 44416768);
  float* xg     = (float*)(ws + 46513920);
  u16*   states = (u16*)(ws + 71679744);
  u16*   hs     = (u16*)(ws + 75874048);
  u16*   qb     = (u16*)(ws + 77971200);
  u16*   kb     = (u16*)(ws + 79019776);
  float* gws    = (float*)(ws + 80068352);
  float* gated  = (float*)(ws + 80076544);
  int*   sorted = (int*)(ws + 88465152);
  float* out = (float*)d_out;

  hipMemsetAsync(hslot, 0, 16384, stream);   // h0 = 0 with tag 0
  detect_kernel<<<dim3(1), dim3(64), 0, stream>>>((const u32*)emb, flag, scal, lam, ms);

  #define CONV(src, dst, n) conv_kernel<<<dim3(((n)+255)/256), dim3(256), 0, stream>>>(src, dst, n, flag)
  CONV(emb,   c_emb, V_ * E_);
  CONV(W_ih,  c_Wih, 3 * H_ * E_);
  convh_kernel<<<dim3((3 * H_ * H_ + 255) / 256), dim3(256), 0, stream>>>(W_hh, c_Whh, 3 * H_ * H_, flag);
  CONV(Wq,    c_Wq,  M_ * H_);
  CONV(Wk,    c_Wk,  M_ * H_);
  CONV(Wg,    c_Wg,  H_);
  CONV(Whe,   c_Whe, E_ * H_);
  CONV(b_ih,  c_bih, 3 * H_);
  CONV(b_hh,  c_bhh, 3 * H_);
  CONV(bq,    c_bq,  M_);
  CONV(bk,    c_bk,  M_);
  CONV(bg,    c_bg,  1);
  CONV(bhe,   c_bhe, E_);
  CONV(obias, c_ob,  V_);
  CONV(smW,   c_smW, GC_);
  #undef CONV

  smear_kernel<<<dim3(B_ * S_), dim3(64), 0, stream>>>(ids, c_emb, c_smW, scal, xs);
  gemm_bt<false><<<dim3(3072 / 128, 2048 / 128), dim3(256), 0, stream>>>(xs, c_Wih, c_bih, (void*)xg, E_, 3072);
  gru_kernel<<<dim3(64), dim3(1024), 0, stream>>>(xg, c_Whh, c_bhh, hslot, states);
  gemm_bt<true><<<dim3(512 / 128, 16), dim3(256), 0, stream>>>(states, c_Whe, c_bhe, (void*)hs, H_, 512);
  gemm_bt<true><<<dim3(256 / 128, 16), dim3(256), 0, stream>>>(states, c_Wq, c_bq, (void*)qb, H_, 256);
  gemm_bt<true><<<dim3(256 / 128, 16), dim3(256), 0, stream>>>(states, c_Wk, c_bk, (void*)kb, H_, 256);
  gk_kernel<<<dim3(512), dim3(256), 0, stream>>>(states, c_Wg, c_bg, gws);
  sort_kernel<<<dim3(B_), dim3(1024), 0, stream>>>(ids, sorted);
  attn_kernel<<<dim3(S_, B_), dim3(256), 0, stream>>>(qb, kb, gws, scal, gated);
  gemm_bt<false><<<dim3(V_ / 128, 16), dim3(256), 0, stream>>>(hs, c_emb, c_ob, (void*)out, E_, V_);
  scatter_kernel<<<dim3(B_ * S_ * S_ / 256), dim3(256), 0, stream>>>(sorted, gated, out);
}

// Round 10
// 2625.631 us; speedup vs baseline: 1.3270x; 1.0185x over previous
//
#include <hip/hip_runtime.h>
#include <stdint.h>

#define V_ 32000
#define E_ 512
#define H_ 1024
#define M_ 256
#define B_ 2
#define S_ 1024
#define GC_ 24

typedef unsigned short u16;
typedef unsigned int u32;
typedef unsigned long long u64;

typedef __attribute__((ext_vector_type(8))) short short8;
typedef __attribute__((ext_vector_type(4))) float floatx4;
typedef __attribute__((ext_vector_type(2))) float floatx2;
typedef __attribute__((ext_vector_type(2))) _Float16 halfx2;

__device__ __forceinline__ float bf2f(u16 u){ return __uint_as_float(((u32)u) << 16); }
__device__ __forceinline__ float bflo(u32 u){ return __uint_as_float(u << 16); }
__device__ __forceinline__ float bfhi(u32 u){ return __uint_as_float(u & 0xffff0000u); }
__device__ __forceinline__ u16 f2bf(float f){
  u32 u = __float_as_uint(f);
  u32 r = (u + 0x7fffu + ((u >> 16) & 1u)) >> 16;
  return (u16)r;
}
__device__ __forceinline__ float sigm(float x){ return 1.f / (1.f + __expf(-x)); }

// 2-wide f16 dot product accumulating into f32 (v_dot2_f32_f16); graceful fallback.
__device__ __forceinline__ float dot2f16(u32 a, u32 b, float c){
#if __has_builtin(__builtin_amdgcn_fdot2)
  return __builtin_amdgcn_fdot2(__builtin_bit_cast(halfx2, a),
                                __builtin_bit_cast(halfx2, b), c, false);
#else
  halfx2 av = __builtin_bit_cast(halfx2, a);
  halfx2 bv = __builtin_bit_cast(halfx2, b);
  return fmaf((float)av.y, (float)bv.y, fmaf((float)av.x, (float)bv.x, c));
#endif
}

// ---------------- dtype probe: low-u16-as-bf16 plausibility test on emb ----------------
__global__ __launch_bounds__(64) void detect_kernel(const u32* __restrict__ emb,
    int* __restrict__ flag, float* __restrict__ scal,
    const void* __restrict__ lam, const void* __restrict__ ms)
{
  int lane = threadIdx.x;
  int c = 0;
  for (int i = lane; i < 256; i += 64){
    u32 w = emb[i];
    float a = fabsf(__uint_as_float((w & 0xffffu) << 16));
    if (a > 1e-5f && a < 1.0f) c++;
  }
  #pragma unroll
  for (int o = 32; o; o >>= 1) c += __shfl_down(c, o, 64);
  if (lane == 0){
    int isf32 = (c < 128) ? 1 : 0;
    *flag = isf32;
    if (isf32) scal[0] = ((const float*)lam)[0];
    else {
      float v = bf2f(((const u16*)lam)[0]);
      scal[0] = (fabsf(v) <= 4.0f) ? v : ((const float*)lam)[0];
    }
    if (isf32) scal[1] = ((const float*)ms)[0];
    else {
      u16 a = ((const u16*)ms)[0];
      float v = bf2f(a);
      scal[1] = (a != 0 && fabsf(v) > 1e-4f && fabsf(v) < 1e4f) ? v : ((const float*)ms)[0];
    }
  }
}

// ---------------- canonicalize any float input to bf16 ----------------
__global__ __launch_bounds__(256) void conv_kernel(const void* __restrict__ src,
    u16* __restrict__ dst, int n, const int* __restrict__ flag)
{
  int i = blockIdx.x * 256 + threadIdx.x;
  if (i >= n) return;
  if (*flag) dst[i] = f2bf(((const float*)src)[i]);
  else       dst[i] = ((const u16*)src)[i];
}

// ---------------- canonicalize to f16 (for GRU W_hh: used by v_dot2_f32_f16) ----------------
__global__ __launch_bounds__(256) void convh_kernel(const void* __restrict__ src,
    u16* __restrict__ dst, int n, const int* __restrict__ flag)
{
  int i = blockIdx.x * 256 + threadIdx.x;
  if (i >= n) return;
  float v = (*flag) ? ((const float*)src)[i] : bf2f(((const u16*)src)[i]);
  _Float16 h = (_Float16)v;
  dst[i] = __builtin_bit_cast(u16, h);
}

// ---------------- smear: x' = emb[ids]; x'[t] += lam*sigmoid(x[t,:24]@smW)*x[t-1] ----------------
__global__ __launch_bounds__(64) void smear_kernel(const int* __restrict__ ids,
    const u16* __restrict__ emb, const u16* __restrict__ smW,
    const float* __restrict__ scal, u16* __restrict__ xs)
{
  int row = blockIdx.x;                 // b*S + t
  int t = row & (S_ - 1);
  int lane = threadIdx.x;
  int id = ids[row];
  const u16* er = emb + (size_t)id * E_;
  float sg = 0.f;
  if (t > 0){
    float p = 0.f;
    if (lane < GC_) p = bf2f(er[lane]) * bf2f(smW[lane]);
    #pragma unroll
    for (int o = 32; o; o >>= 1) p += __shfl_down(p, o, 64);
    float dot = __shfl(p, 0, 64);
    sg = scal[0] * sigm(dot);
  }
  uint4 cur = ((const uint4*)er)[lane];
  uint4 outv = cur;
  if (t > 0){
    const u16* ep = emb + (size_t)ids[row - 1] * E_;
    uint4 prv = ((const uint4*)ep)[lane];
    const u16* cu = (const u16*)&cur;
    const u16* pu = (const u16*)&prv;
    u16* po = (u16*)&outv;
    #pragma unroll
    for (int j = 0; j < 8; j++) po[j] = f2bf(bf2f(cu[j]) + sg * bf2f(pu[j]));
  }
  ((uint4*)(xs + (size_t)row * E_))[lane] = outv;
}

// ---------------- generic MFMA GEMM: C(M,N) = A(M,K) * Bm(N,K)^T + bias(N) ----------------
template<bool OUT_BF16>
__global__ __launch_bounds__(256) void gemm_bt(
    const u16* __restrict__ A, const u16* __restrict__ Bm,
    const u16* __restrict__ bias, void* __restrict__ Cout,
    int K, int Ndim)
{
  int wave = threadIdx.x >> 6, lane = threadIdx.x & 63;
  int wm = wave >> 1, wn = wave & 1;
  int m0 = blockIdx.y * 128 + wm * 64;
  int n0 = blockIdx.x * 128 + wn * 64;
  int lrow = lane & 15, lq = lane >> 4;
  floatx4 acc[4][4];
  #pragma unroll
  for (int i = 0; i < 4; i++)
    #pragma unroll
    for (int j = 0; j < 4; j++) acc[i][j] = (floatx4)0.f;
  const u16* Ab = A + (size_t)(m0 + lrow) * K + lq * 8;
  const u16* Bb = Bm + (size_t)(n0 + lrow) * K + lq * 8;
  for (int k0 = 0; k0 < K; k0 += 32){
    short8 af[4], bfr[4];
    #pragma unroll
    for (int tt = 0; tt < 4; tt++)
      af[tt] = *(const short8*)(Ab + (size_t)tt * 16 * K + k0);
    #pragma unroll
    for (int tt = 0; tt < 4; tt++)
      bfr[tt] = *(const short8*)(Bb + (size_t)tt * 16 * K + k0);
    #pragma unroll
    for (int im = 0; im < 4; im++)
      #pragma unroll
      for (int in = 0; in < 4; in++)
        acc[im][in] = __builtin_amdgcn_mfma_f32_16x16x32_bf16(af[im], bfr[in], acc[im][in], 0, 0, 0);
  }
  #pragma unroll
  for (int in = 0; in < 4; in++){
    int n = n0 + in * 16 + lrow;
    float bv = bf2f(bias[n]);
    #pragma unroll
    for (int im = 0; im < 4; im++){
      int mb = m0 + im * 16 + lq * 4;
      #pragma unroll
      for (int r = 0; r < 4; r++){
        float v = acc[im][in][r] + bv;
        size_t off = (size_t)(mb + r) * Ndim + n;
        if (OUT_BF16) ((u16*)Cout)[off] = f2bf(v);
        else          ((float*)Cout)[off] = v;
      }
    }
  }
}

// ---------------- GRU persistent scan: 64 WGs x 1024 thr (v10, session best — unchanged) ----------------
__global__ __launch_bounds__(1024) void gru_kernel(
    const float* __restrict__ xg, const u16* __restrict__ W_hh,
    const u16* __restrict__ b_hh, u32* __restrict__ hslot,
    u16* __restrict__ states)
{
  const int b = blockIdx.x >> 5;
  const int ibase = (blockIdx.x & 31) * 32;
  const int tid = threadIdx.x;
  const int kg = tid >> 5;     // 32-k chunk [0,32); uniform per half-wave
  const int il = tid & 31;
  const int i = ibase + il;    // output this thread contributes to
  const int w = tid >> 6;      // wave id [0,16)

  __shared__ u32   lds_hpk[2][H_ / 2];  // packed f16 pairs of h (parity-dbuf)
  __shared__ float red[3][16][32];      // cross-wave partials (barrier-protected)

  // resident weights: 3 gates x 32 k f16 for (output i, k-chunk kg)
  uint4 Wv[3][4];
  #pragma unroll
  for (int g = 0; g < 3; g++){
    const uint4* p = (const uint4*)(W_hh + ((size_t)(g * H_ + i)) * H_ + kg * 32);
    #pragma unroll
    for (int q = 0; q < 4; q++) Wv[g][q] = p[q];
  }

  // tail-only state (wave 0, lanes 0-31): h_old, biases, xg(t) in registers
  float ho = 0.f, xr0 = 0.f, xz0 = 0.f, xn0 = 0.f, bh0 = 0.f, bh1 = 0.f, bh2 = 0.f;
  if (tid < 32){
    bh0 = bf2f(b_hh[ibase + tid]);
    bh1 = bf2f(b_hh[H_ + ibase + tid]);
    bh2 = bf2f(b_hh[2 * H_ + ibase + tid]);
    size_t base = ((size_t)(b * S_)) * 3072 + ibase + tid;
    xr0 = xg[base]; xz0 = xg[base + 1024]; xn0 = xg[base + 2048];
  }

  for (int t = 0; t < S_; t++){
    const int p = t & 1;
    // ---- poll + stage: 512 lanes, one u64 (2 tagged-u32 slots) each ----
    if (tid < 512){
      const u64* rp = (const u64*)(hslot + ((size_t)((p ^ 1) * B_ + b)) * H_) + tid;
      const u32 tg = (u32)t;
      u64 u0;
      do {
        u0 = __hip_atomic_load(rp, __ATOMIC_RELAXED, __HIP_MEMORY_SCOPE_AGENT);
      } while ((((u32)(u0 >> 16) & 0xffffu) != tg) | (((u32)(u0 >> 48)) != tg));
      lds_hpk[p][tid] = ((u32)u0 & 0xffffu) | (((u32)(u0 >> 32)) << 16);
    }
    __syncthreads();
    // ---- matvec partials: 48 dot2 over this thread's 32-k chunk (broadcast reads) ----
    const u32* hp = &lds_hpk[p][kg * 16];
    float pr = 0.f, pz = 0.f, pn = 0.f;
    #pragma unroll
    for (int q = 0; q < 4; q++){
      uint4 wr = Wv[0][q], wz = Wv[1][q], wn4 = Wv[2][q];
      u32 cr[4] = {wr.x, wr.y, wr.z, wr.w};
      u32 cz[4] = {wz.x, wz.y, wz.z, wz.w};
      u32 cn[4] = {wn4.x, wn4.y, wn4.z, wn4.w};
      #pragma unroll
      for (int e = 0; e < 4; e++){
        u32 h2 = hp[q * 4 + e];
        pr = dot2f16(cr[e], h2, pr);
        pz = dot2f16(cz[e], h2, pz);
        pn = dot2f16(cn[e], h2, pn);
      }
    }
    // combine the wave's two 32-k chunks, write per-wave partials
    pr += __shfl_xor(pr, 32, 64);
    pz += __shfl_xor(pz, 32, 64);
    pn += __shfl_xor(pn, 32, 64);
    if ((tid & 63) < 32){
      red[0][w][il] = pr; red[1][w][il] = pz; red[2][w][il] = pn;
    }
    __syncthreads();
    // ---- tail: wave 0 lanes 0-31 finalize; publish FIRST, then states/prefetch ----
    if (tid < 32){
      __builtin_amdgcn_s_setprio(1);
      float hr = 0.f, hz = 0.f, hn = 0.f;
      #pragma unroll
      for (int ww = 0; ww < 16; ww++){
        hr += red[0][ww][tid]; hz += red[1][ww][tid]; hn += red[2][ww][tid];
      }
      float r = sigm(xr0 + hr + bh0);
      float z = sigm(xz0 + hz + bh1);
      float xx = xn0 + r * (hn + bh2);
      float ax = fabsf(xx);
      float et = __expf(-2.f * ax);                     // overflow-safe fast tanh
      float n = copysignf((1.f - et) * __builtin_amdgcn_rcpf(1.f + et), xx);
      float hnew = (1.f - z) * n + z * ho;
      ho = hnew;
      u16 h16 = __builtin_bit_cast(u16, (_Float16)hnew);
      u32 tgv = (((u32)(t + 1)) << 16) | (u32)h16;
      __hip_atomic_store(&hslot[((size_t)(p * B_ + b)) * H_ + ibase + tid], tgv,
                         __ATOMIC_RELAXED, __HIP_MEMORY_SCOPE_AGENT);
      __builtin_amdgcn_s_setprio(0);
      states[((size_t)(b * S_ + t)) * H_ + ibase + tid] = f2bf(hnew);
      if (t + 1 < S_){
        size_t base = ((size_t)(b * S_ + t + 1)) * 3072 + ibase + tid;
        xr0 = xg[base]; xz0 = xg[base + 1024]; xn0 = xg[base + 2048];
      }
    }
  }
}

// ---------------- g gate: sigmoid(states @ Wg + bg) ----------------
__global__ __launch_bounds__(256) void gk_kernel(const u16* __restrict__ states,
    const u16* __restrict__ Wg, const u16* __restrict__ bg, float* __restrict__ gws)
{
  int row = blockIdx.x * 4 + (threadIdx.x >> 6);
  int lane = threadIdx.x & 63;
  const u16* sr = states + (size_t)row * H_;
  float p = 0.f;
  #pragma unroll
  for (int j = 0; j < 16; j++){
    int c = j * 64 + lane;
    p += bf2f(sr[c]) * bf2f(Wg[c]);
  }
  #pragma unroll
  for (int o = 32; o; o >>= 1) p += __shfl_xor(p, o, 64);
  if (lane == 0) gws[row] = sigm(p + bf2f(bg[0]));
}

// ---------------- bitonic sort of (id<<11 | t) per batch ----------------
__global__ __launch_bounds__(1024) void sort_kernel(const int* __restrict__ ids, int* __restrict__ sorted)
{
  int b = blockIdx.x, tid = threadIdx.x;
  __shared__ int arr[S_];
  arr[tid] = (ids[b * S_ + tid] << 11) | tid;
  __syncthreads();
  for (int k = 2; k <= S_; k <<= 1){
    for (int j = k >> 1; j > 0; j >>= 1){
      int ixj = tid ^ j;
      if (ixj > tid){
        int a = arr[tid], c = arr[ixj];
        bool dir = (tid & k) == 0;
        if (dir ? (a > c) : (a < c)){ arr[tid] = c; arr[ixj] = a; }
      }
      __syncthreads();
    }
  }
  sorted[b * S_ + tid] = arr[tid];
}

// ---------------- attention v11: scores precomputed by MFMA GEMM ----------------
// scores[b][s][t] = q[b,s,:] . k[b,t,:]  (fp32, unscaled). This kernel reads its
// row COALESCED, applies 1/sqrt(M)=0.0625, then the identical masked-softmax +
// g*mscale normalization and gated write as before.
__global__ __launch_bounds__(256) void attn_kernel(
    const float* __restrict__ scores, const float* __restrict__ gws,
    const float* __restrict__ scal, float* __restrict__ gated)
{
  int s = blockIdx.x, b = blockIdx.y;
  if (s == 0) return;
  int tid = threadIdx.x;
  __shared__ float rbm[4], rbs[4];
  const float* srow = scores + ((size_t)(b * S_ + s)) * S_;
  float myS[4];
  float lmax = -1e30f;
  #pragma unroll
  for (int r = 0; r < 4; r++){
    int t = tid + 256 * r;
    if (t < s){
      float d = srow[t] * 0.0625f;       // 1/sqrt(256)
      myS[r] = d;
      lmax = fmaxf(lmax, d);
    }
  }
  #pragma unroll
  for (int o = 32; o; o >>= 1) lmax = fmaxf(lmax, __shfl_xor(lmax, o, 64));
  if ((tid & 63) == 0) rbm[tid >> 6] = lmax;
  __syncthreads();
  float gmax = fmaxf(fmaxf(rbm[0], rbm[1]), fmaxf(rbm[2], rbm[3]));
  float lsum = 0.f;
  #pragma unroll
  for (int r = 0; r < 4; r++){
    int t = tid + 256 * r;
    if (t < s){ myS[r] = __expf(myS[r] - gmax); lsum += myS[r]; }
  }
  #pragma unroll
  for (int o = 32; o; o >>= 1) lsum += __shfl_xor(lsum, o, 64);
  if ((tid & 63) == 0) rbs[tid >> 6] = lsum;
  __syncthreads();
  float gsum = rbs[0] + rbs[1] + rbs[2] + rbs[3];
  float fac = gws[b * S_ + s] * scal[1] / gsum;
  float* grow = gated + ((size_t)(b * S_ + s)) * S_;
  #pragma unroll
  for (int r = 0; r < 4; r++){
    int t = tid + 256 * r;
    if (t < s) grow[t] = myS[r] * fac;
  }
}

// ---------------- scatter: out[b,s,ids[b,t]] += gated[b,s,t] (dup-merged, race-free, fp32) ----------------
__global__ __launch_bounds__(256) void scatter_kernel(
    const int* __restrict__ sorted, const float* __restrict__ gated,
    float* __restrict__ out)
{
  int gid = blockIdx.x * 256 + threadIdx.x;
  int e = gid & (S_ - 1);
  int row = gid >> 10;                  // b*S + s
  int s = row & (S_ - 1);
  int b = row >> 10;
  const int* sb = sorted + b * S_;
  int pk = sb[e];
  int v = pk >> 11;
  if (e > 0 && (sb[e - 1] >> 11) == v) return;   // only leaders
  const float* grow = gated + (size_t)row * S_;
  float sum = 0.f; bool any = false;
  for (int j = e; j < S_; j++){
    int pj = sb[j];
    if ((pj >> 11) != v) break;
    int t = pj & 2047;
    if (t < s){ sum += grow[t]; any = true; }
  }
  if (any){
    size_t off = (size_t)row * V_ + v;
    out[off] += sum;
  }
}

extern "C" void kernel_launch(void* const* d_in, const int* in_sizes, int n_in,
                              void* d_out, int out_size, void* d_ws, size_t ws_size,
                              hipStream_t stream)
{
  const int*  ids   = (const int*)d_in[0];
  const void* emb   = d_in[1];
  const void* W_ih  = d_in[2];
  const void* W_hh  = d_in[3];
  const void* b_ih  = d_in[4];
  const void* b_hh  = d_in[5];
  const void* Wq    = d_in[6];
  const void* bq    = d_in[7];
  const void* Wk    = d_in[8];
  const void* bk    = d_in[9];
  const void* Wg    = d_in[10];
  const void* bg    = d_in[11];
  const void* Whe   = d_in[12];
  const void* bhe   = d_in[13];
  const void* obias = d_in[14];
  const void* ms    = d_in[15];
  const void* smW   = d_in[16];
  const void* lam   = d_in[17];
  (void)in_sizes; (void)n_in; (void)out_size; (void)ws_size;

  char* ws = (char*)d_ws;
  int*   flag   = (int*)(ws + 0);
  float* scal   = (float*)(ws + 256);
  u32*   hslot  = (u32*)(ws + 512);        // [2][B][H] tagged-f16 u32 slots (16 KB)
  u16*   zbias  = (u16*)(ws + 16896);      // 2 KB of bf16 zeros (scores-GEMM bias)
  u16*   c_emb  = (u16*)(ws + 33280);
  u16*   c_Wih  = (u16*)(ws + 32801280);
  u16*   c_Whh  = (u16*)(ws + 35947008);   // f16 content (GRU dot2 path)
  u16*   c_Wq   = (u16*)(ws + 42238464);
  u16*   c_Wk   = (u16*)(ws + 42762752);
  u16*   c_Wg   = (u16*)(ws + 43287040);
  u16*   c_Whe  = (u16*)(ws + 43289088);
  u16*   c_bih  = (u16*)(ws + 44337664);
  u16*   c_bhh  = (u16*)(ws + 44343808);
  u16*   c_bq   = (u16*)(ws + 44349952);
  u16*   c_bk   = (u16*)(ws + 44350464);
  u16*   c_bg   = (u16*)(ws + 44350976);
  u16*   c_bhe  = (u16*)(ws + 44351232);
  u16*   c_ob   = (u16*)(ws + 44352256);
  u16*   c_smW  = (u16*)(ws + 44416512);
  u16*   xs     = (u16*)(ws + 44416768);
  float* xg     = (float*)(ws + 46513920);
  u16*   states = (u16*)(ws + 71679744);
  u16*   hs     = (u16*)(ws + 75874048);
  u16*   qb     = (u16*)(ws + 77971200);
  u16*   kb     = (u16*)(ws + 79019776);
  float* gws    = (float*)(ws + 80068352);
  float* gated  = (float*)(ws + 80076544);
  int*   sorted = (int*)(ws + 88465152);
  float* scores = xg;                      // xg region (25 MB) is dead after gru; reuse (needs 8.4 MB)
  float* out = (float*)d_out;

  hipMemsetAsync(hslot, 0, 16384, stream);   // h0 = 0 with tag 0
  hipMemsetAsync(zbias, 0, 2048, stream);    // zero bias for scores GEMM
  detect_kernel<<<dim3(1), dim3(64), 0, stream>>>((const u32*)emb, flag, scal, lam, ms);

  #define CONV(src, dst, n) conv_kernel<<<dim3(((n)+255)/256), dim3(256), 0, stream>>>(src, dst, n, flag)
  CONV(emb,   c_emb, V_ * E_);
  CONV(W_ih,  c_Wih, 3 * H_ * E_);
  convh_kernel<<<dim3((3 * H_ * H_ + 255) / 256), dim3(256), 0, stream>>>(W_hh, c_Whh, 3 * H_ * H_, flag);
  CONV(Wq,    c_Wq,  M_ * H_);
  CONV(Wk,    c_Wk,  M_ * H_);
  CONV(Wg,    c_Wg,  H_);
  CONV(Whe,   c_Whe, E_ * H_);
  CONV(b_ih,  c_bih, 3 * H_);
  CONV(b_hh,  c_bhh, 3 * H_);
  CONV(bq,    c_bq,  M_);
  CONV(bk,    c_bk,  M_);
  CONV(bg,    c_bg,  1);
  CONV(bhe,   c_bhe, E_);
  CONV(obias, c_ob,  V_);
  CONV(smW,   c_smW, GC_);
  #undef CONV

  smear_kernel<<<dim3(B_ * S_), dim3(64), 0, stream>>>(ids, c_emb, c_smW, scal, xs);
  gemm_bt<false><<<dim3(3072 / 128, 2048 / 128), dim3(256), 0, stream>>>(xs, c_Wih, c_bih, (void*)xg, E_, 3072);
  gru_kernel<<<dim3(64), dim3(1024), 0, stream>>>(xg, c_Whh, c_bhh, hslot, states);
  gemm_bt<true><<<dim3(512 / 128, 16), dim3(256), 0, stream>>>(states, c_Whe, c_bhe, (void*)hs, H_, 512);
  gemm_bt<true><<<dim3(256 / 128, 16), dim3(256), 0, stream>>>(states, c_Wq, c_bq, (void*)qb, H_, 256);
  gemm_bt<true><<<dim3(256 / 128, 16), dim3(256), 0, stream>>>(states, c_Wk, c_bk, (void*)kb, H_, 256);
  // scores[b] = q[b] @ k[b]^T (M=S, N=S, K=M_), fp32 out, zero bias — MFMA replaces
  // attn's scattered per-thread dot loads (writes into dead xg region)
  gemm_bt<false><<<dim3(S_ / 128, S_ / 128), dim3(256), 0, stream>>>(qb, kb, zbias, (void*)scores, M_, S_);
  gemm_bt<false><<<dim3(S_ / 128, S_ / 128), dim3(256), 0, stream>>>(qb + (size_t)S_ * M_, kb + (size_t)S_ * M_,
                                                                     zbias, (void*)(scores + (size_t)S_ * S_), M_, S_);
  gk_kernel<<<dim3(512), dim3(256), 0, stream>>>(states, c_Wg, c_bg, gws);
  sort_kernel<<<dim3(B_), dim3(1024), 0, stream>>>(ids, sorted);
  attn_kernel<<<dim3(S_, B_), dim3(256), 0, stream>>>(scores, gws, scal, gated);
  gemm_bt<false><<<dim3(V_ / 128, 16), dim3(256), 0, stream>>>(hs, c_emb, c_ob, (void*)out, E_, V_);
  scatter_kernel<<<dim3(B_ * S_ * S_ / 256), dim3(256), 0, stream>>>(sorted, gated, out);
}

// Round 11
// 2527.606 us; speedup vs baseline: 1.3785x; 1.0388x over previous
//
#include <hip/hip_runtime.h>
#include <stdint.h>

#define V_ 32000
#define E_ 512
#define H_ 1024
#define M_ 256
#define B_ 2
#define S_ 1024
#define GC_ 24

typedef unsigned short u16;
typedef unsigned int u32;
typedef unsigned long long u64;

typedef __attribute__((ext_vector_type(8))) short short8;
typedef __attribute__((ext_vector_type(4))) float floatx4;
typedef __attribute__((ext_vector_type(2))) float floatx2;
typedef __attribute__((ext_vector_type(2))) _Float16 halfx2;

__device__ __forceinline__ float bf2f(u16 u){ return __uint_as_float(((u32)u) << 16); }
__device__ __forceinline__ float bflo(u32 u){ return __uint_as_float(u << 16); }
__device__ __forceinline__ float bfhi(u32 u){ return __uint_as_float(u & 0xffff0000u); }
__device__ __forceinline__ u16 f2bf(float f){
  u32 u = __float_as_uint(f);
  u32 r = (u + 0x7fffu + ((u >> 16) & 1u)) >> 16;
  return (u16)r;
}
__device__ __forceinline__ float sigm(float x){ return 1.f / (1.f + __expf(-x)); }

// 2-wide f16 dot product accumulating into f32 (v_dot2_f32_f16); graceful fallback.
__device__ __forceinline__ float dot2f16(u32 a, u32 b, float c){
#if __has_builtin(__builtin_amdgcn_fdot2)
  return __builtin_amdgcn_fdot2(__builtin_bit_cast(halfx2, a),
                                __builtin_bit_cast(halfx2, b), c, false);
#else
  halfx2 av = __builtin_bit_cast(halfx2, a);
  halfx2 bv = __builtin_bit_cast(halfx2, b);
  return fmaf((float)av.y, (float)bv.y, fmaf((float)av.x, (float)bv.x, c));
#endif
}

// async global->LDS 16B (wave-uniform LDS base + lane*16 scatter; per-lane global src)
__device__ __forceinline__ void gload_lds16(const void* g, void* l){
  __builtin_amdgcn_global_load_lds(
      (const __attribute__((address_space(1))) void*)g,
      (__attribute__((address_space(3))) void*)l, 16, 0, 0);
}

// ---------------- dtype probe: low-u16-as-bf16 plausibility test on emb ----------------
__global__ __launch_bounds__(64) void detect_kernel(const u32* __restrict__ emb,
    int* __restrict__ flag, float* __restrict__ scal,
    const void* __restrict__ lam, const void* __restrict__ ms)
{
  int lane = threadIdx.x;
  int c = 0;
  for (int i = lane; i < 256; i += 64){
    u32 w = emb[i];
    float a = fabsf(__uint_as_float((w & 0xffffu) << 16));
    if (a > 1e-5f && a < 1.0f) c++;
  }
  #pragma unroll
  for (int o = 32; o; o >>= 1) c += __shfl_down(c, o, 64);
  if (lane == 0){
    int isf32 = (c < 128) ? 1 : 0;
    *flag = isf32;
    if (isf32) scal[0] = ((const float*)lam)[0];
    else {
      float v = bf2f(((const u16*)lam)[0]);
      scal[0] = (fabsf(v) <= 4.0f) ? v : ((const float*)lam)[0];
    }
    if (isf32) scal[1] = ((const float*)ms)[0];
    else {
      u16 a = ((const u16*)ms)[0];
      float v = bf2f(a);
      scal[1] = (a != 0 && fabsf(v) > 1e-4f && fabsf(v) < 1e4f) ? v : ((const float*)ms)[0];
    }
  }
}

// ---------------- merged canonicalization: all 15 tensors in ONE launch ----------------
// Segment table is compile-time (sizes + ws dst offsets); src pointers by value.
// Numerics identical to the old conv/convh kernels per segment.
struct ConvArgs { const void* s[15]; };

#define CONV_TOTAL 22191385
__global__ __launch_bounds__(256) void convall_kernel(ConvArgs a, char* __restrict__ ws,
                                                      const int* __restrict__ flag)
{
  static const int    ns[15]    = {16384000, 1572864, 3145728, 262144, 262144, 1024,
                                   524288, 3072, 3072, 256, 256, 1, 512, 32000, 24};
  static const size_t doffs[15] = {33280, 32801280, 35947008, 42238464, 42762752,
                                   43287040, 43289088, 44337664, 44343808, 44349952,
                                   44350464, 44350976, 44351232, 44352256, 44416512};
  int gid = blockIdx.x * 256 + threadIdx.x;
  if (gid >= CONV_TOTAL) return;
  int isf32 = *flag;
  int seg = -1, r = gid;
  #pragma unroll
  for (int k = 0; k < 15; k++){
    if (seg < 0){ if (r < ns[k]) seg = k; else r -= ns[k]; }
  }
  const void* src = a.s[seg];
  u16* dst = (u16*)(ws + doffs[seg]);
  if (seg == 2){   // W_hh -> f16 (GRU dot2 path)
    float v = isf32 ? ((const float*)src)[r] : bf2f(((const u16*)src)[r]);
    dst[r] = __builtin_bit_cast(u16, (_Float16)v);
  } else {         // bf16 canonical
    dst[r] = isf32 ? f2bf(((const float*)src)[r]) : ((const u16*)src)[r];
  }
}

// ---------------- smear: x' = emb[ids]; x'[t] += lam*sigmoid(x[t,:24]@smW)*x[t-1] ----------------
__global__ __launch_bounds__(64) void smear_kernel(const int* __restrict__ ids,
    const u16* __restrict__ emb, const u16* __restrict__ smW,
    const float* __restrict__ scal, u16* __restrict__ xs)
{
  int row = blockIdx.x;                 // b*S + t
  int t = row & (S_ - 1);
  int lane = threadIdx.x;
  int id = ids[row];
  const u16* er = emb + (size_t)id * E_;
  float sg = 0.f;
  if (t > 0){
    float p = 0.f;
    if (lane < GC_) p = bf2f(er[lane]) * bf2f(smW[lane]);
    #pragma unroll
    for (int o = 32; o; o >>= 1) p += __shfl_down(p, o, 64);
    float dot = __shfl(p, 0, 64);
    sg = scal[0] * sigm(dot);
  }
  uint4 cur = ((const uint4*)er)[lane];
  uint4 outv = cur;
  if (t > 0){
    const u16* ep = emb + (size_t)ids[row - 1] * E_;
    uint4 prv = ((const uint4*)ep)[lane];
    const u16* cu = (const u16*)&cur;
    const u16* pu = (const u16*)&prv;
    u16* po = (u16*)&outv;
    #pragma unroll
    for (int j = 0; j < 8; j++) po[j] = f2bf(bf2f(cu[j]) + sg * bf2f(pu[j]));
  }
  ((uint4*)(xs + (size_t)row * E_))[lane] = outv;
}

// ---------------- generic MFMA GEMM: C(M,N) = A(M,K) * Bm(N,K)^T + bias(N) ----------------
template<bool OUT_BF16>
__global__ __launch_bounds__(256) void gemm_bt(
    const u16* __restrict__ A, const u16* __restrict__ Bm,
    const u16* __restrict__ bias, void* __restrict__ Cout,
    int K, int Ndim)
{
  int wave = threadIdx.x >> 6, lane = threadIdx.x & 63;
  int wm = wave >> 1, wn = wave & 1;
  int m0 = blockIdx.y * 128 + wm * 64;
  int n0 = blockIdx.x * 128 + wn * 64;
  int lrow = lane & 15, lq = lane >> 4;
  floatx4 acc[4][4];
  #pragma unroll
  for (int i = 0; i < 4; i++)
    #pragma unroll
    for (int j = 0; j < 4; j++) acc[i][j] = (floatx4)0.f;
  const u16* Ab = A + (size_t)(m0 + lrow) * K + lq * 8;
  const u16* Bb = Bm + (size_t)(n0 + lrow) * K + lq * 8;
  for (int k0 = 0; k0 < K; k0 += 32){
    short8 af[4], bfr[4];
    #pragma unroll
    for (int tt = 0; tt < 4; tt++)
      af[tt] = *(const short8*)(Ab + (size_t)tt * 16 * K + k0);
    #pragma unroll
    for (int tt = 0; tt < 4; tt++)
      bfr[tt] = *(const short8*)(Bb + (size_t)tt * 16 * K + k0);
    #pragma unroll
    for (int im = 0; im < 4; im++)
      #pragma unroll
      for (int in = 0; in < 4; in++)
        acc[im][in] = __builtin_amdgcn_mfma_f32_16x16x32_bf16(af[im], bfr[in], acc[im][in], 0, 0, 0);
  }
  #pragma unroll
  for (int in = 0; in < 4; in++){
    int n = n0 + in * 16 + lrow;
    float bv = bf2f(bias[n]);
    #pragma unroll
    for (int im = 0; im < 4; im++){
      int mb = m0 + im * 16 + lq * 4;
      #pragma unroll
      for (int r = 0; r < 4; r++){
        float v = acc[im][in][r] + bv;
        size_t off = (size_t)(mb + r) * Ndim + n;
        if (OUT_BF16) ((u16*)Cout)[off] = f2bf(v);
        else          ((float*)Cout)[off] = v;
      }
    }
  }
}

// ---------------- LDS-staged MFMA GEMM (m97 structure) for the big V-GEMM ----------------
// 128x128 tile, BK=32, global_load_lds width-16 staging of A+B tiles (16 KB LDS,
// single-buffered, 2 barriers per K-step). Fragment map + epilogue identical to
// gemm_bt<false>. Used ONLY for out = hs @ emb^T + obias (K=512, N=32000).
__global__ __launch_bounds__(256) void gemm_v(
    const u16* __restrict__ A, const u16* __restrict__ Bm,
    const u16* __restrict__ bias, float* __restrict__ Cout,
    int K, int Ndim)
{
  __shared__ u16 la[128 * 32];
  __shared__ u16 lb[128 * 32];
  int wave = threadIdx.x >> 6, lane = threadIdx.x & 63;
  int wm = wave >> 1, wn = wave & 1;
  int tm0 = blockIdx.y * 128, tn0 = blockIdx.x * 128;
  int m0 = tm0 + wm * 64;
  int n0 = tn0 + wn * 64;
  int lrow = lane & 15, lq = lane >> 4;
  floatx4 acc[4][4];
  #pragma unroll
  for (int i = 0; i < 4; i++)
    #pragma unroll
    for (int j = 0; j < 4; j++) acc[i][j] = (floatx4)0.f;

  const int o = wave * 1024 + lane * 16;     // this lane's byte offset in the 8KB tile
  for (int k0 = 0; k0 < K; k0 += 32){
    // stage A and B tiles: 2 issues each per wave (wave-uniform LDS base)
    #pragma unroll
    for (int j = 0; j < 2; j++){
      int oo = o + j * 4096;
      int row = oo >> 6;                     // 64B per row (32 bf16)
      int ce  = (oo & 63) >> 1;              // element offset in row
      gload_lds16(&A[(size_t)(tm0 + row) * K + k0 + ce],  &la[(wave * 1024 + j * 4096) >> 1]);
      gload_lds16(&Bm[(size_t)(tn0 + row) * K + k0 + ce], &lb[(wave * 1024 + j * 4096) >> 1]);
    }
    __syncthreads();                          // drains vmcnt (compiler-inserted) + barrier
    short8 af[4], bfr[4];
    #pragma unroll
    for (int tt = 0; tt < 4; tt++)
      af[tt] = *(const short8*)&la[(wm * 64 + tt * 16 + lrow) * 32 + lq * 8];
    #pragma unroll
    for (int tt = 0; tt < 4; tt++)
      bfr[tt] = *(const short8*)&lb[(wn * 64 + tt * 16 + lrow) * 32 + lq * 8];
    #pragma unroll
    for (int im = 0; im < 4; im++)
      #pragma unroll
      for (int in = 0; in < 4; in++)
        acc[im][in] = __builtin_amdgcn_mfma_f32_16x16x32_bf16(af[im], bfr[in], acc[im][in], 0, 0, 0);
    __syncthreads();                          // protect LDS before next stage
  }
  #pragma unroll
  for (int in = 0; in < 4; in++){
    int n = n0 + in * 16 + lrow;
    float bv = bf2f(bias[n]);
    #pragma unroll
    for (int im = 0; im < 4; im++){
      int mb = m0 + im * 16 + lq * 4;
      #pragma unroll
      for (int r = 0; r < 4; r++)
        Cout[(size_t)(mb + r) * Ndim + n] = acc[im][in][r] + bv;
    }
  }
}

// ---------------- GRU persistent scan: 64 WGs x 1024 thr (v10, session best — unchanged) ----------------
__global__ __launch_bounds__(1024) void gru_kernel(
    const float* __restrict__ xg, const u16* __restrict__ W_hh,
    const u16* __restrict__ b_hh, u32* __restrict__ hslot,
    u16* __restrict__ states)
{
  const int b = blockIdx.x >> 5;
  const int ibase = (blockIdx.x & 31) * 32;
  const int tid = threadIdx.x;
  const int kg = tid >> 5;     // 32-k chunk [0,32); uniform per half-wave
  const int il = tid & 31;
  const int i = ibase + il;    // output this thread contributes to
  const int w = tid >> 6;      // wave id [0,16)

  __shared__ u32   lds_hpk[2][H_ / 2];  // packed f16 pairs of h (parity-dbuf)
  __shared__ float red[3][16][32];      // cross-wave partials (barrier-protected)

  // resident weights: 3 gates x 32 k f16 for (output i, k-chunk kg)
  uint4 Wv[3][4];
  #pragma unroll
  for (int g = 0; g < 3; g++){
    const uint4* p = (const uint4*)(W_hh + ((size_t)(g * H_ + i)) * H_ + kg * 32);
    #pragma unroll
    for (int q = 0; q < 4; q++) Wv[g][q] = p[q];
  }

  // tail-only state (wave 0, lanes 0-31): h_old, biases, xg(t) in registers
  float ho = 0.f, xr0 = 0.f, xz0 = 0.f, xn0 = 0.f, bh0 = 0.f, bh1 = 0.f, bh2 = 0.f;
  if (tid < 32){
    bh0 = bf2f(b_hh[ibase + tid]);
    bh1 = bf2f(b_hh[H_ + ibase + tid]);
    bh2 = bf2f(b_hh[2 * H_ + ibase + tid]);
    size_t base = ((size_t)(b * S_)) * 3072 + ibase + tid;
    xr0 = xg[base]; xz0 = xg[base + 1024]; xn0 = xg[base + 2048];
  }

  for (int t = 0; t < S_; t++){
    const int p = t & 1;
    // ---- poll + stage: 512 lanes, one u64 (2 tagged-u32 slots) each ----
    if (tid < 512){
      const u64* rp = (const u64*)(hslot + ((size_t)((p ^ 1) * B_ + b)) * H_) + tid;
      const u32 tg = (u32)t;
      u64 u0;
      do {
        u0 = __hip_atomic_load(rp, __ATOMIC_RELAXED, __HIP_MEMORY_SCOPE_AGENT);
      } while ((((u32)(u0 >> 16) & 0xffffu) != tg) | (((u32)(u0 >> 48)) != tg));
      lds_hpk[p][tid] = ((u32)u0 & 0xffffu) | (((u32)(u0 >> 32)) << 16);
    }
    __syncthreads();
    // ---- matvec partials: 48 dot2 over this thread's 32-k chunk (broadcast reads) ----
    const u32* hp = &lds_hpk[p][kg * 16];
    float pr = 0.f, pz = 0.f, pn = 0.f;
    #pragma unroll
    for (int q = 0; q < 4; q++){
      uint4 wr = Wv[0][q], wz = Wv[1][q], wn4 = Wv[2][q];
      u32 cr[4] = {wr.x, wr.y, wr.z, wr.w};
      u32 cz[4] = {wz.x, wz.y, wz.z, wz.w};
      u32 cn[4] = {wn4.x, wn4.y, wn4.z, wn4.w};
      #pragma unroll
      for (int e = 0; e < 4; e++){
        u32 h2 = hp[q * 4 + e];
        pr = dot2f16(cr[e], h2, pr);
        pz = dot2f16(cz[e], h2, pz);
        pn = dot2f16(cn[e], h2, pn);
      }
    }
    // combine the wave's two 32-k chunks, write per-wave partials
    pr += __shfl_xor(pr, 32, 64);
    pz += __shfl_xor(pz, 32, 64);
    pn += __shfl_xor(pn, 32, 64);
    if ((tid & 63) < 32){
      red[0][w][il] = pr; red[1][w][il] = pz; red[2][w][il] = pn;
    }
    __syncthreads();
    // ---- tail: wave 0 lanes 0-31 finalize; publish FIRST, then states/prefetch ----
    if (tid < 32){
      __builtin_amdgcn_s_setprio(1);
      float hr = 0.f, hz = 0.f, hn = 0.f;
      #pragma unroll
      for (int ww = 0; ww < 16; ww++){
        hr += red[0][ww][tid]; hz += red[1][ww][tid]; hn += red[2][ww][tid];
      }
      float r = sigm(xr0 + hr + bh0);
      float z = sigm(xz0 + hz + bh1);
      float xx = xn0 + r * (hn + bh2);
      float ax = fabsf(xx);
      float et = __expf(-2.f * ax);                     // overflow-safe fast tanh
      float n = copysignf((1.f - et) * __builtin_amdgcn_rcpf(1.f + et), xx);
      float hnew = (1.f - z) * n + z * ho;
      ho = hnew;
      u16 h16 = __builtin_bit_cast(u16, (_Float16)hnew);
      u32 tgv = (((u32)(t + 1)) << 16) | (u32)h16;
      __hip_atomic_store(&hslot[((size_t)(p * B_ + b)) * H_ + ibase + tid], tgv,
                         __ATOMIC_RELAXED, __HIP_MEMORY_SCOPE_AGENT);
      __builtin_amdgcn_s_setprio(0);
      states[((size_t)(b * S_ + t)) * H_ + ibase + tid] = f2bf(hnew);
      if (t + 1 < S_){
        size_t base = ((size_t)(b * S_ + t + 1)) * 3072 + ibase + tid;
        xr0 = xg[base]; xz0 = xg[base + 1024]; xn0 = xg[base + 2048];
      }
    }
  }
}

// ---------------- g gate: sigmoid(states @ Wg + bg) ----------------
__global__ __launch_bounds__(256) void gk_kernel(const u16* __restrict__ states,
    const u16* __restrict__ Wg, const u16* __restrict__ bg, float* __restrict__ gws)
{
  int row = blockIdx.x * 4 + (threadIdx.x >> 6);
  int lane = threadIdx.x & 63;
  const u16* sr = states + (size_t)row * H_;
  float p = 0.f;
  #pragma unroll
  for (int j = 0; j < 16; j++){
    int c = j * 64 + lane;
    p += bf2f(sr[c]) * bf2f(Wg[c]);
  }
  #pragma unroll
  for (int o = 32; o; o >>= 1) p += __shfl_xor(p, o, 64);
  if (lane == 0) gws[row] = sigm(p + bf2f(bg[0]));
}

// ---------------- bitonic sort of (id<<11 | t) per batch ----------------
__global__ __launch_bounds__(1024) void sort_kernel(const int* __restrict__ ids, int* __restrict__ sorted)
{
  int b = blockIdx.x, tid = threadIdx.x;
  __shared__ int arr[S_];
  arr[tid] = (ids[b * S_ + tid] << 11) | tid;
  __syncthreads();
  for (int k = 2; k <= S_; k <<= 1){
    for (int j = k >> 1; j > 0; j >>= 1){
      int ixj = tid ^ j;
      if (ixj > tid){
        int a = arr[tid], c = arr[ixj];
        bool dir = (tid & k) == 0;
        if (dir ? (a > c) : (a < c)){ arr[tid] = c; arr[ixj] = a; }
      }
      __syncthreads();
    }
  }
  sorted[b * S_ + tid] = arr[tid];
}

// ---------------- attention: scores precomputed by MFMA GEMM ----------------
__global__ __launch_bounds__(256) void attn_kernel(
    const float* __restrict__ scores, const float* __restrict__ gws,
    const float* __restrict__ scal, float* __restrict__ gated)
{
  int s = blockIdx.x, b = blockIdx.y;
  if (s == 0) return;
  int tid = threadIdx.x;
  __shared__ float rbm[4], rbs[4];
  const float* srow = scores + ((size_t)(b * S_ + s)) * S_;
  float myS[4];
  float lmax = -1e30f;
  #pragma unroll
  for (int r = 0; r < 4; r++){
    int t = tid + 256 * r;
    if (t < s){
      float d = srow[t] * 0.0625f;       // 1/sqrt(256)
      myS[r] = d;
      lmax = fmaxf(lmax, d);
    }
  }
  #pragma unroll
  for (int o = 32; o; o >>= 1) lmax = fmaxf(lmax, __shfl_xor(lmax, o, 64));
  if ((tid & 63) == 0) rbm[tid >> 6] = lmax;
  __syncthreads();
  float gmax = fmaxf(fmaxf(rbm[0], rbm[1]), fmaxf(rbm[2], rbm[3]));
  float lsum = 0.f;
  #pragma unroll
  for (int r = 0; r < 4; r++){
    int t = tid + 256 * r;
    if (t < s){ myS[r] = __expf(myS[r] - gmax); lsum += myS[r]; }
  }
  #pragma unroll
  for (int o = 32; o; o >>= 1) lsum += __shfl_xor(lsum, o, 64);
  if ((tid & 63) == 0) rbs[tid >> 6] = lsum;
  __syncthreads();
  float gsum = rbs[0] + rbs[1] + rbs[2] + rbs[3];
  float fac = gws[b * S_ + s] * scal[1] / gsum;
  float* grow = gated + ((size_t)(b * S_ + s)) * S_;
  #pragma unroll
  for (int r = 0; r < 4; r++){
    int t = tid + 256 * r;
    if (t < s) grow[t] = myS[r] * fac;
  }
}

// ---------------- scatter: out[b,s,ids[b,t]] += gated[b,s,t] (dup-merged, race-free, fp32) ----------------
__global__ __launch_bounds__(256) void scatter_kernel(
    const int* __restrict__ sorted, const float* __restrict__ gated,
    float* __restrict__ out)
{
  int gid = blockIdx.x * 256 + threadIdx.x;
  int e = gid & (S_ - 1);
  int row = gid >> 10;                  // b*S + s
  int s = row & (S_ - 1);
  int b = row >> 10;
  const int* sb = sorted + b * S_;
  int pk = sb[e];
  int v = pk >> 11;
  if (e > 0 && (sb[e - 1] >> 11) == v) return;   // only leaders
  const float* grow = gated + (size_t)row * S_;
  float sum = 0.f; bool any = false;
  for (int j = e; j < S_; j++){
    int pj = sb[j];
    if ((pj >> 11) != v) break;
    int t = pj & 2047;
    if (t < s){ sum += grow[t]; any = true; }
  }
  if (any){
    size_t off = (size_t)row * V_ + v;
    out[off] += sum;
  }
}

extern "C" void kernel_launch(void* const* d_in, const int* in_sizes, int n_in,
                              void* d_out, int out_size, void* d_ws, size_t ws_size,
                              hipStream_t stream)
{
  const int*  ids   = (const int*)d_in[0];
  const void* emb   = d_in[1];
  const void* W_ih  = d_in[2];
  const void* W_hh  = d_in[3];
  const void* b_ih  = d_in[4];
  const void* b_hh  = d_in[5];
  const void* Wq    = d_in[6];
  const void* bq    = d_in[7];
  const void* Wk    = d_in[8];
  const void* bk    = d_in[9];
  const void* Wg    = d_in[10];
  const void* bg    = d_in[11];
  const void* Whe   = d_in[12];
  const void* bhe   = d_in[13];
  const void* obias = d_in[14];
  const void* ms    = d_in[15];
  const void* smW   = d_in[16];
  const void* lam   = d_in[17];
  (void)in_sizes; (void)n_in; (void)out_size; (void)ws_size;

  char* ws = (char*)d_ws;
  int*   flag   = (int*)(ws + 0);
  float* scal   = (float*)(ws + 256);
  u32*   hslot  = (u32*)(ws + 512);        // [2][B][H] tagged-f16 u32 slots (16 KB)
  u16*   zbias  = (u16*)(ws + 16896);      // 2 KB of bf16 zeros (scores-GEMM bias)
  u16*   c_emb  = (u16*)(ws + 33280);
  u16*   c_Wih  = (u16*)(ws + 32801280);
  u16*   c_Whh  = (u16*)(ws + 35947008);   // f16 content (GRU dot2 path)
  u16*   c_Wq   = (u16*)(ws + 42238464);
  u16*   c_Wk   = (u16*)(ws + 42762752);
  u16*   c_Wg   = (u16*)(ws + 43287040);
  u16*   c_Whe  = (u16*)(ws + 43289088);
  u16*   c_bih  = (u16*)(ws + 44337664);
  u16*   c_bhh  = (u16*)(ws + 44343808);
  u16*   c_bq   = (u16*)(ws + 44349952);
  u16*   c_bk   = (u16*)(ws + 44350464);
  u16*   c_bg   = (u16*)(ws + 44350976);
  u16*   c_bhe  = (u16*)(ws + 44351232);
  u16*   c_ob   = (u16*)(ws + 44352256);
  u16*   c_smW  = (u16*)(ws + 44416512);
  u16*   xs     = (u16*)(ws + 44416768);
  float* xg     = (float*)(ws + 46513920);
  u16*   states = (u16*)(ws + 71679744);
  u16*   hs     = (u16*)(ws + 75874048);
  u16*   qb     = (u16*)(ws + 77971200);
  u16*   kb     = (u16*)(ws + 79019776);
  float* gws    = (float*)(ws + 80068352);
  float* gated  = (float*)(ws + 80076544);
  int*   sorted = (int*)(ws + 88465152);
  float* scores = xg;                      // xg region (25 MB) dead after gru; reuse (needs 8.4 MB)
  float* out = (float*)d_out;

  hipMemsetAsync(hslot, 0, 16384, stream);   // h0 = 0 with tag 0
  hipMemsetAsync(zbias, 0, 2048, stream);    // zero bias for scores GEMM
  detect_kernel<<<dim3(1), dim3(64), 0, stream>>>((const u32*)emb, flag, scal, lam, ms);

  // single merged conversion launch (was 15 separate kernels)
  ConvArgs ca;
  ca.s[0] = emb;  ca.s[1] = W_ih; ca.s[2] = W_hh; ca.s[3] = Wq;   ca.s[4] = Wk;
  ca.s[5] = Wg;   ca.s[6] = Whe;  ca.s[7] = b_ih; ca.s[8] = b_hh; ca.s[9] = bq;
  ca.s[10] = bk;  ca.s[11] = bg;  ca.s[12] = bhe; ca.s[13] = obias; ca.s[14] = smW;
  convall_kernel<<<dim3((CONV_TOTAL + 255) / 256), dim3(256), 0, stream>>>(ca, ws, flag);

  smear_kernel<<<dim3(B_ * S_), dim3(64), 0, stream>>>(ids, c_emb, c_smW, scal, xs);
  gemm_bt<false><<<dim3(3072 / 128, 2048 / 128), dim3(256), 0, stream>>>(xs, c_Wih, c_bih, (void*)xg, E_, 3072);
  gru_kernel<<<dim3(64), dim3(1024), 0, stream>>>(xg, c_Whh, c_bhh, hslot, states);
  gemm_bt<true><<<dim3(512 / 128, 16), dim3(256), 0, stream>>>(states, c_Whe, c_bhe, (void*)hs, H_, 512);
  gemm_bt<true><<<dim3(256 / 128, 16), dim3(256), 0, stream>>>(states, c_Wq, c_bq, (void*)qb, H_, 256);
  gemm_bt<true><<<dim3(256 / 128, 16), dim3(256), 0, stream>>>(states, c_Wk, c_bk, (void*)kb, H_, 256);
  // scores[b] = q[b] @ k[b]^T (fp32, zero bias) via MFMA
  gemm_bt<false><<<dim3(S_ / 128, S_ / 128), dim3(256), 0, stream>>>(qb, kb, zbias, (void*)scores, M_, S_);
  gemm_bt<false><<<dim3(S_ / 128, S_ / 128), dim3(256), 0, stream>>>(qb + (size_t)S_ * M_, kb + (size_t)S_ * M_,
                                                                     zbias, (void*)(scores + (size_t)S_ * S_), M_, S_);
  gk_kernel<<<dim3(512), dim3(256), 0, stream>>>(states, c_Wg, c_bg, gws);
  sort_kernel<<<dim3(B_), dim3(1024), 0, stream>>>(ids, sorted);
  attn_kernel<<<dim3(S_, B_), dim3(256), 0, stream>>>(scores, gws, scal, gated);
  // big V-GEMM: LDS-staged m97-style kernel (was no-LDS gemm_bt)
  gemm_v<<<dim3(V_ / 128, 16), dim3(256), 0, stream>>>(hs, c_emb, c_ob, out, E_, V_);
  scatter_kernel<<<dim3(B_ * S_ * S_ / 256), dim3(256), 0, stream>>>(sorted, gated, out);
}

// Round 12
// 2483.792 us; speedup vs baseline: 1.4028x; 1.0176x over previous
//
#include <hip/hip_runtime.h>
#include <stdint.h>

#define V_ 32000
#define E_ 512
#define H_ 1024
#define M_ 256
#define B_ 2
#define S_ 1024
#define GC_ 24

typedef unsigned short u16;
typedef unsigned int u32;
typedef unsigned long long u64;

typedef __attribute__((ext_vector_type(8))) short short8;
typedef __attribute__((ext_vector_type(4))) float floatx4;
typedef __attribute__((ext_vector_type(2))) float floatx2;
typedef __attribute__((ext_vector_type(2))) _Float16 halfx2;

__device__ __forceinline__ float bf2f(u16 u){ return __uint_as_float(((u32)u) << 16); }
__device__ __forceinline__ float bflo(u32 u){ return __uint_as_float(u << 16); }
__device__ __forceinline__ float bfhi(u32 u){ return __uint_as_float(u & 0xffff0000u); }
__device__ __forceinline__ u16 f2bf(float f){
  u32 u = __float_as_uint(f);
  u32 r = (u + 0x7fffu + ((u >> 16) & 1u)) >> 16;
  return (u16)r;
}
__device__ __forceinline__ float sigm(float x){ return 1.f / (1.f + __expf(-x)); }

// 2-wide f16 dot product accumulating into f32 (v_dot2_f32_f16); graceful fallback.
__device__ __forceinline__ float dot2f16(u32 a, u32 b, float c){
#if __has_builtin(__builtin_amdgcn_fdot2)
  return __builtin_amdgcn_fdot2(__builtin_bit_cast(halfx2, a),
                                __builtin_bit_cast(halfx2, b), c, false);
#else
  halfx2 av = __builtin_bit_cast(halfx2, a);
  halfx2 bv = __builtin_bit_cast(halfx2, b);
  return fmaf((float)av.y, (float)bv.y, fmaf((float)av.x, (float)bv.x, c));
#endif
}

// async global->LDS 16B (wave-uniform LDS base + lane*16 scatter; per-lane global src)
__device__ __forceinline__ void gload_lds16(const void* g, void* l){
  __builtin_amdgcn_global_load_lds(
      (const __attribute__((address_space(1))) void*)g,
      (__attribute__((address_space(3))) void*)l, 16, 0, 0);
}

// ---------------- dtype probe: low-u16-as-bf16 plausibility test on emb ----------------
__global__ __launch_bounds__(64) void detect_kernel(const u32* __restrict__ emb,
    int* __restrict__ flag, float* __restrict__ scal,
    const void* __restrict__ lam, const void* __restrict__ ms)
{
  int lane = threadIdx.x;
  int c = 0;
  for (int i = lane; i < 256; i += 64){
    u32 w = emb[i];
    float a = fabsf(__uint_as_float((w & 0xffffu) << 16));
    if (a > 1e-5f && a < 1.0f) c++;
  }
  #pragma unroll
  for (int o = 32; o; o >>= 1) c += __shfl_down(c, o, 64);
  if (lane == 0){
    int isf32 = (c < 128) ? 1 : 0;
    *flag = isf32;
    if (isf32) scal[0] = ((const float*)lam)[0];
    else {
      float v = bf2f(((const u16*)lam)[0]);
      scal[0] = (fabsf(v) <= 4.0f) ? v : ((const float*)lam)[0];
    }
    if (isf32) scal[1] = ((const float*)ms)[0];
    else {
      u16 a = ((const u16*)ms)[0];
      float v = bf2f(a);
      scal[1] = (a != 0 && fabsf(v) > 1e-4f && fabsf(v) < 1e4f) ? v : ((const float*)ms)[0];
    }
  }
}

// ---------------- merged canonicalization: all 15 tensors in ONE launch ----------------
struct ConvArgs { const void* s[15]; };

#define CONV_TOTAL 22191385
__global__ __launch_bounds__(256) void convall_kernel(ConvArgs a, char* __restrict__ ws,
                                                      const int* __restrict__ flag)
{
  static const int    ns[15]    = {16384000, 1572864, 3145728, 262144, 262144, 1024,
                                   524288, 3072, 3072, 256, 256, 1, 512, 32000, 24};
  static const size_t doffs[15] = {33280, 32801280, 35947008, 42238464, 42762752,
                                   43287040, 43289088, 44337664, 44343808, 44349952,
                                   44350464, 44350976, 44351232, 44352256, 44416512};
  int gid = blockIdx.x * 256 + threadIdx.x;
  if (gid >= CONV_TOTAL) return;
  int isf32 = *flag;
  int seg = -1, r = gid;
  #pragma unroll
  for (int k = 0; k < 15; k++){
    if (seg < 0){ if (r < ns[k]) seg = k; else r -= ns[k]; }
  }
  const void* src = a.s[seg];
  u16* dst = (u16*)(ws + doffs[seg]);
  if (seg == 2){   // W_hh -> f16 (GRU dot2 path)
    float v = isf32 ? ((const float*)src)[r] : bf2f(((const u16*)src)[r]);
    dst[r] = __builtin_bit_cast(u16, (_Float16)v);
  } else {         // bf16 canonical
    dst[r] = isf32 ? f2bf(((const float*)src)[r]) : ((const u16*)src)[r];
  }
}

// ---------------- smear: x' = emb[ids]; x'[t] += lam*sigmoid(x[t,:24]@smW)*x[t-1] ----------------
__global__ __launch_bounds__(64) void smear_kernel(const int* __restrict__ ids,
    const u16* __restrict__ emb, const u16* __restrict__ smW,
    const float* __restrict__ scal, u16* __restrict__ xs)
{
  int row = blockIdx.x;                 // b*S + t
  int t = row & (S_ - 1);
  int lane = threadIdx.x;
  int id = ids[row];
  const u16* er = emb + (size_t)id * E_;
  float sg = 0.f;
  if (t > 0){
    float p = 0.f;
    if (lane < GC_) p = bf2f(er[lane]) * bf2f(smW[lane]);
    #pragma unroll
    for (int o = 32; o; o >>= 1) p += __shfl_down(p, o, 64);
    float dot = __shfl(p, 0, 64);
    sg = scal[0] * sigm(dot);
  }
  uint4 cur = ((const uint4*)er)[lane];
  uint4 outv = cur;
  if (t > 0){
    const u16* ep = emb + (size_t)ids[row - 1] * E_;
    uint4 prv = ((const uint4*)ep)[lane];
    const u16* cu = (const u16*)&cur;
    const u16* pu = (const u16*)&prv;
    u16* po = (u16*)&outv;
    #pragma unroll
    for (int j = 0; j < 8; j++) po[j] = f2bf(bf2f(cu[j]) + sg * bf2f(pu[j]));
  }
  ((uint4*)(xs + (size_t)row * E_))[lane] = outv;
}

// ---------------- generic MFMA GEMM: C(M,N) = A(M,K) * Bm(N,K)^T + bias(N) ----------------
template<bool OUT_BF16>
__global__ __launch_bounds__(256) void gemm_bt(
    const u16* __restrict__ A, const u16* __restrict__ Bm,
    const u16* __restrict__ bias, void* __restrict__ Cout,
    int K, int Ndim)
{
  int wave = threadIdx.x >> 6, lane = threadIdx.x & 63;
  int wm = wave >> 1, wn = wave & 1;
  int m0 = blockIdx.y * 128 + wm * 64;
  int n0 = blockIdx.x * 128 + wn * 64;
  int lrow = lane & 15, lq = lane >> 4;
  floatx4 acc[4][4];
  #pragma unroll
  for (int i = 0; i < 4; i++)
    #pragma unroll
    for (int j = 0; j < 4; j++) acc[i][j] = (floatx4)0.f;
  const u16* Ab = A + (size_t)(m0 + lrow) * K + lq * 8;
  const u16* Bb = Bm + (size_t)(n0 + lrow) * K + lq * 8;
  for (int k0 = 0; k0 < K; k0 += 32){
    short8 af[4], bfr[4];
    #pragma unroll
    for (int tt = 0; tt < 4; tt++)
      af[tt] = *(const short8*)(Ab + (size_t)tt * 16 * K + k0);
    #pragma unroll
    for (int tt = 0; tt < 4; tt++)
      bfr[tt] = *(const short8*)(Bb + (size_t)tt * 16 * K + k0);
    #pragma unroll
    for (int im = 0; im < 4; im++)
      #pragma unroll
      for (int in = 0; in < 4; in++)
        acc[im][in] = __builtin_amdgcn_mfma_f32_16x16x32_bf16(af[im], bfr[in], acc[im][in], 0, 0, 0);
  }
  #pragma unroll
  for (int in = 0; in < 4; in++){
    int n = n0 + in * 16 + lrow;
    float bv = bf2f(bias[n]);
    #pragma unroll
    for (int im = 0; im < 4; im++){
      int mb = m0 + im * 16 + lq * 4;
      #pragma unroll
      for (int r = 0; r < 4; r++){
        float v = acc[im][in][r] + bv;
        size_t off = (size_t)(mb + r) * Ndim + n;
        if (OUT_BF16) ((u16*)Cout)[off] = f2bf(v);
        else          ((float*)Cout)[off] = v;
      }
    }
  }
}

// ---------------- LDS-staged MFMA GEMM (m97 structure) for the big V-GEMM ----------------
// v13: block mapping transposed — M-tile from blockIdx.x (extent 16), N-tile from
// blockIdx.y (extent 250). Dispatch order is x-fastest, so 16 consecutive blocks
// share one B (emb) tile -> emb read ONCE (33 MB) instead of 16x (524 MB).
// A (hs, 2 MB) is L2-resident. Staging/fragments/epilogue unchanged from v12.
__global__ __launch_bounds__(256) void gemm_v(
    const u16* __restrict__ A, const u16* __restrict__ Bm,
    const u16* __restrict__ bias, float* __restrict__ Cout,
    int K, int Ndim)
{
  __shared__ u16 la[128 * 32];
  __shared__ u16 lb[128 * 32];
  int wave = threadIdx.x >> 6, lane = threadIdx.x & 63;
  int wm = wave >> 1, wn = wave & 1;
  int tm0 = blockIdx.x * 128, tn0 = blockIdx.y * 128;   // transposed mapping
  int m0 = tm0 + wm * 64;
  int n0 = tn0 + wn * 64;
  int lrow = lane & 15, lq = lane >> 4;
  floatx4 acc[4][4];
  #pragma unroll
  for (int i = 0; i < 4; i++)
    #pragma unroll
    for (int j = 0; j < 4; j++) acc[i][j] = (floatx4)0.f;

  const int o = wave * 1024 + lane * 16;     // this lane's byte offset in the 8KB tile
  for (int k0 = 0; k0 < K; k0 += 32){
    #pragma unroll
    for (int j = 0; j < 2; j++){
      int oo = o + j * 4096;
      int row = oo >> 6;                     // 64B per row (32 bf16)
      int ce  = (oo & 63) >> 1;              // element offset in row
      gload_lds16(&A[(size_t)(tm0 + row) * K + k0 + ce],  &la[(wave * 1024 + j * 4096) >> 1]);
      gload_lds16(&Bm[(size_t)(tn0 + row) * K + k0 + ce], &lb[(wave * 1024 + j * 4096) >> 1]);
    }
    __syncthreads();
    short8 af[4], bfr[4];
    #pragma unroll
    for (int tt = 0; tt < 4; tt++)
      af[tt] = *(const short8*)&la[(wm * 64 + tt * 16 + lrow) * 32 + lq * 8];
    #pragma unroll
    for (int tt = 0; tt < 4; tt++)
      bfr[tt] = *(const short8*)&lb[(wn * 64 + tt * 16 + lrow) * 32 + lq * 8];
    #pragma unroll
    for (int im = 0; im < 4; im++)
      #pragma unroll
      for (int in = 0; in < 4; in++)
        acc[im][in] = __builtin_amdgcn_mfma_f32_16x16x32_bf16(af[im], bfr[in], acc[im][in], 0, 0, 0);
    __syncthreads();
  }
  #pragma unroll
  for (int in = 0; in < 4; in++){
    int n = n0 + in * 16 + lrow;
    float bv = bf2f(bias[n]);
    #pragma unroll
    for (int im = 0; im < 4; im++){
      int mb = m0 + im * 16 + lq * 4;
      #pragma unroll
      for (int r = 0; r < 4; r++)
        Cout[(size_t)(mb + r) * Ndim + n] = acc[im][in][r] + bv;
    }
  }
}

// ---------------- GRU persistent scan + piggybacked sort (grid 66) ----------------
// WGs 0-63: v10 gru (session best, unchanged). WGs 64-65: bitonic sort of
// (id<<11 | t) for batch b = blockIdx.x-64, running in the gru shadow on idle CUs.
__global__ __launch_bounds__(1024) void gru_kernel(
    const float* __restrict__ xg, const u16* __restrict__ W_hh,
    const u16* __restrict__ b_hh, u32* __restrict__ hslot,
    u16* __restrict__ states, const int* __restrict__ ids, int* __restrict__ sorted)
{
  __shared__ int arr[S_];               // sort WGs only
  if (blockIdx.x >= 64){
    int b = blockIdx.x - 64, tid = threadIdx.x;
    arr[tid] = (ids[b * S_ + tid] << 11) | tid;
    __syncthreads();
    for (int k = 2; k <= S_; k <<= 1){
      for (int j = k >> 1; j > 0; j >>= 1){
        int ixj = tid ^ j;
        if (ixj > tid){
          int a = arr[tid], c = arr[ixj];
          bool dir = (tid & k) == 0;
          if (dir ? (a > c) : (a < c)){ arr[tid] = c; arr[ixj] = a; }
        }
        __syncthreads();
      }
    }
    sorted[b * S_ + tid] = arr[tid];
    return;
  }

  const int b = blockIdx.x >> 5;
  const int ibase = (blockIdx.x & 31) * 32;
  const int tid = threadIdx.x;
  const int kg = tid >> 5;     // 32-k chunk [0,32); uniform per half-wave
  const int il = tid & 31;
  const int i = ibase + il;    // output this thread contributes to
  const int w = tid >> 6;      // wave id [0,16)

  __shared__ u32   lds_hpk[2][H_ / 2];  // packed f16 pairs of h (parity-dbuf)
  __shared__ float red[3][16][32];      // cross-wave partials (barrier-protected)

  // resident weights: 3 gates x 32 k f16 for (output i, k-chunk kg)
  uint4 Wv[3][4];
  #pragma unroll
  for (int g = 0; g < 3; g++){
    const uint4* p = (const uint4*)(W_hh + ((size_t)(g * H_ + i)) * H_ + kg * 32);
    #pragma unroll
    for (int q = 0; q < 4; q++) Wv[g][q] = p[q];
  }

  // tail-only state (wave 0, lanes 0-31): h_old, biases, xg(t) in registers
  float ho = 0.f, xr0 = 0.f, xz0 = 0.f, xn0 = 0.f, bh0 = 0.f, bh1 = 0.f, bh2 = 0.f;
  if (tid < 32){
    bh0 = bf2f(b_hh[ibase + tid]);
    bh1 = bf2f(b_hh[H_ + ibase + tid]);
    bh2 = bf2f(b_hh[2 * H_ + ibase + tid]);
    size_t base = ((size_t)(b * S_)) * 3072 + ibase + tid;
    xr0 = xg[base]; xz0 = xg[base + 1024]; xn0 = xg[base + 2048];
  }

  for (int t = 0; t < S_; t++){
    const int p = t & 1;
    // ---- poll + stage: 512 lanes, one u64 (2 tagged-u32 slots) each ----
    if (tid < 512){
      const u64* rp = (const u64*)(hslot + ((size_t)((p ^ 1) * B_ + b)) * H_) + tid;
      const u32 tg = (u32)t;
      u64 u0;
      do {
        u0 = __hip_atomic_load(rp, __ATOMIC_RELAXED, __HIP_MEMORY_SCOPE_AGENT);
      } while ((((u32)(u0 >> 16) & 0xffffu) != tg) | (((u32)(u0 >> 48)) != tg));
      lds_hpk[p][tid] = ((u32)u0 & 0xffffu) | (((u32)(u0 >> 32)) << 16);
    }
    __syncthreads();
    // ---- matvec partials: 48 dot2 over this thread's 32-k chunk (broadcast reads) ----
    const u32* hp = &lds_hpk[p][kg * 16];
    float pr = 0.f, pz = 0.f, pn = 0.f;
    #pragma unroll
    for (int q = 0; q < 4; q++){
      uint4 wr = Wv[0][q], wz = Wv[1][q], wn4 = Wv[2][q];
      u32 cr[4] = {wr.x, wr.y, wr.z, wr.w};
      u32 cz[4] = {wz.x, wz.y, wz.z, wz.w};
      u32 cn[4] = {wn4.x, wn4.y, wn4.z, wn4.w};
      #pragma unroll
      for (int e = 0; e < 4; e++){
        u32 h2 = hp[q * 4 + e];
        pr = dot2f16(cr[e], h2, pr);
        pz = dot2f16(cz[e], h2, pz);
        pn = dot2f16(cn[e], h2, pn);
      }
    }
    // combine the wave's two 32-k chunks, write per-wave partials
    pr += __shfl_xor(pr, 32, 64);
    pz += __shfl_xor(pz, 32, 64);
    pn += __shfl_xor(pn, 32, 64);
    if ((tid & 63) < 32){
      red[0][w][il] = pr; red[1][w][il] = pz; red[2][w][il] = pn;
    }
    __syncthreads();
    // ---- tail: wave 0 lanes 0-31 finalize; publish FIRST, then states/prefetch ----
    if (tid < 32){
      __builtin_amdgcn_s_setprio(1);
      float hr = 0.f, hz = 0.f, hn = 0.f;
      #pragma unroll
      for (int ww = 0; ww < 16; ww++){
        hr += red[0][ww][tid]; hz += red[1][ww][tid]; hn += red[2][ww][tid];
      }
      float r = sigm(xr0 + hr + bh0);
      float z = sigm(xz0 + hz + bh1);
      float xx = xn0 + r * (hn + bh2);
      float ax = fabsf(xx);
      float et = __expf(-2.f * ax);                     // overflow-safe fast tanh
      float n = copysignf((1.f - et) * __builtin_amdgcn_rcpf(1.f + et), xx);
      float hnew = (1.f - z) * n + z * ho;
      ho = hnew;
      u16 h16 = __builtin_bit_cast(u16, (_Float16)hnew);
      u32 tgv = (((u32)(t + 1)) << 16) | (u32)h16;
      __hip_atomic_store(&hslot[((size_t)(p * B_ + b)) * H_ + ibase + tid], tgv,
                         __ATOMIC_RELAXED, __HIP_MEMORY_SCOPE_AGENT);
      __builtin_amdgcn_s_setprio(0);
      states[((size_t)(b * S_ + t)) * H_ + ibase + tid] = f2bf(hnew);
      if (t + 1 < S_){
        size_t base = ((size_t)(b * S_ + t + 1)) * 3072 + ibase + tid;
        xr0 = xg[base]; xz0 = xg[base + 1024]; xn0 = xg[base + 2048];
      }
    }
  }
}

// ---------------- g gate: sigmoid(states @ Wg + bg) ----------------
__global__ __launch_bounds__(256) void gk_kernel(const u16* __restrict__ states,
    const u16* __restrict__ Wg, const u16* __restrict__ bg, float* __restrict__ gws)
{
  int row = blockIdx.x * 4 + (threadIdx.x >> 6);
  int lane = threadIdx.x & 63;
  const u16* sr = states + (size_t)row * H_;
  float p = 0.f;
  #pragma unroll
  for (int j = 0; j < 16; j++){
    int c = j * 64 + lane;
    p += bf2f(sr[c]) * bf2f(Wg[c]);
  }
  #pragma unroll
  for (int o = 32; o; o >>= 1) p += __shfl_xor(p, o, 64);
  if (lane == 0) gws[row] = sigm(p + bf2f(bg[0]));
}

// ---------------- fused attention + scatter (runs AFTER gemm_v) ----------------
// Phase 1 (attn): identical masked-softmax from precomputed scores; the gated row
// stays in LDS (no global gated buffer). Phase 2 (scatter): stage sorted[b] in
// LDS; leader threads sum duplicate-token contributions from the LDS row and do
// the exclusive += into out. Math and summation order identical to v12's pair.
__global__ __launch_bounds__(256) void attn_scatter_kernel(
    const float* __restrict__ scores, const float* __restrict__ gws,
    const float* __restrict__ scal, const int* __restrict__ sorted,
    float* __restrict__ out)
{
  int s = blockIdx.x, b = blockIdx.y;
  if (s == 0) return;
  int tid = threadIdx.x;
  __shared__ float grow[S_];
  __shared__ int   sb[S_];
  __shared__ float rbm[4], rbs[4];
  const float* srow = scores + ((size_t)(b * S_ + s)) * S_;
  #pragma unroll
  for (int r = 0; r < 4; r++) sb[tid + 256 * r] = sorted[b * S_ + tid + 256 * r];
  float myS[4];
  float lmax = -1e30f;
  #pragma unroll
  for (int r = 0; r < 4; r++){
    int t = tid + 256 * r;
    if (t < s){
      float d = srow[t] * 0.0625f;       // 1/sqrt(256)
      myS[r] = d;
      lmax = fmaxf(lmax, d);
    }
  }
  #pragma unroll
  for (int o = 32; o; o >>= 1) lmax = fmaxf(lmax, __shfl_xor(lmax, o, 64));
  if ((tid & 63) == 0) rbm[tid >> 6] = lmax;
  __syncthreads();
  float gmax = fmaxf(fmaxf(rbm[0], rbm[1]), fmaxf(rbm[2], rbm[3]));
  float lsum = 0.f;
  #pragma unroll
  for (int r = 0; r < 4; r++){
    int t = tid + 256 * r;
    if (t < s){ myS[r] = __expf(myS[r] - gmax); lsum += myS[r]; }
  }
  #pragma unroll
  for (int o = 32; o; o >>= 1) lsum += __shfl_xor(lsum, o, 64);
  if ((tid & 63) == 0) rbs[tid >> 6] = lsum;
  __syncthreads();
  float gsum = rbs[0] + rbs[1] + rbs[2] + rbs[3];
  float fac = gws[b * S_ + s] * scal[1] / gsum;
  #pragma unroll
  for (int r = 0; r < 4; r++){
    int t = tid + 256 * r;
    if (t < s) grow[t] = myS[r] * fac;
  }
  __syncthreads();
  // ---- scatter phase: leaders merge duplicates from LDS, exclusive += into out ----
  float* orow = out + ((size_t)(b * S_ + s)) * V_;
  #pragma unroll
  for (int r = 0; r < 4; r++){
    int e = tid + 256 * r;
    int pk = sb[e];
    int v = pk >> 11;
    if (e > 0 && (sb[e - 1] >> 11) == v) continue;   // only leaders
    float sum = 0.f; bool any = false;
    for (int j = e; j < S_; j++){
      int pj = sb[j];
      if ((pj >> 11) != v) break;
      int t = pj & 2047;
      if (t < s){ sum += grow[t]; any = true; }
    }
    if (any) orow[v] += sum;
  }
}

extern "C" void kernel_launch(void* const* d_in, const int* in_sizes, int n_in,
                              void* d_out, int out_size, void* d_ws, size_t ws_size,
                              hipStream_t stream)
{
  const int*  ids   = (const int*)d_in[0];
  const void* emb   = d_in[1];
  const void* W_ih  = d_in[2];
  const void* W_hh  = d_in[3];
  const void* b_ih  = d_in[4];
  const void* b_hh  = d_in[5];
  const void* Wq    = d_in[6];
  const void* bq    = d_in[7];
  const void* Wk    = d_in[8];
  const void* bk    = d_in[9];
  const void* Wg    = d_in[10];
  const void* bg    = d_in[11];
  const void* Whe   = d_in[12];
  const void* bhe   = d_in[13];
  const void* obias = d_in[14];
  const void* ms    = d_in[15];
  const void* smW   = d_in[16];
  const void* lam   = d_in[17];
  (void)in_sizes; (void)n_in; (void)out_size; (void)ws_size;

  char* ws = (char*)d_ws;
  int*   flag   = (int*)(ws + 0);
  float* scal   = (float*)(ws + 256);
  u32*   hslot  = (u32*)(ws + 512);        // [2][B][H] tagged-f16 u32 slots (16 KB)
  u16*   zbias  = (u16*)(ws + 16896);      // 2 KB of bf16 zeros (scores-GEMM bias)
  u16*   c_emb  = (u16*)(ws + 33280);
  u16*   c_Wih  = (u16*)(ws + 32801280);
  u16*   c_Whh  = (u16*)(ws + 35947008);   // f16 content (GRU dot2 path)
  u16*   c_Wq   = (u16*)(ws + 42238464);
  u16*   c_Wk   = (u16*)(ws + 42762752);
  u16*   c_Wg   = (u16*)(ws + 43287040);
  u16*   c_Whe  = (u16*)(ws + 43289088);
  u16*   c_bih  = (u16*)(ws + 44337664);
  u16*   c_bhh  = (u16*)(ws + 44343808);
  u16*   c_bq   = (u16*)(ws + 44349952);
  u16*   c_bk   = (u16*)(ws + 44350464);
  u16*   c_bg   = (u16*)(ws + 44350976);
  u16*   c_bhe  = (u16*)(ws + 44351232);
  u16*   c_ob   = (u16*)(ws + 44352256);
  u16*   c_smW  = (u16*)(ws + 44416512);
  u16*   xs     = (u16*)(ws + 44416768);
  float* xg     = (float*)(ws + 46513920);
  u16*   states = (u16*)(ws + 71679744);
  u16*   hs     = (u16*)(ws + 75874048);
  u16*   qb     = (u16*)(ws + 77971200);
  u16*   kb     = (u16*)(ws + 79019776);
  float* gws    = (float*)(ws + 80068352);
  int*   sorted = (int*)(ws + 88465152);
  float* scores = xg;                      // xg region (25 MB) dead after gru; reuse (needs 8.4 MB)
  float* out = (float*)d_out;

  hipMemsetAsync(hslot, 0, 16384, stream);   // h0 = 0 with tag 0
  hipMemsetAsync(zbias, 0, 2048, stream);    // zero bias for scores GEMM
  detect_kernel<<<dim3(1), dim3(64), 0, stream>>>((const u32*)emb, flag, scal, lam, ms);

  // single merged conversion launch
  ConvArgs ca;
  ca.s[0] = emb;  ca.s[1] = W_ih; ca.s[2] = W_hh; ca.s[3] = Wq;   ca.s[4] = Wk;
  ca.s[5] = Wg;   ca.s[6] = Whe;  ca.s[7] = b_ih; ca.s[8] = b_hh; ca.s[9] = bq;
  ca.s[10] = bk;  ca.s[11] = bg;  ca.s[12] = bhe; ca.s[13] = obias; ca.s[14] = smW;
  convall_kernel<<<dim3((CONV_TOTAL + 255) / 256), dim3(256), 0, stream>>>(ca, ws, flag);

  smear_kernel<<<dim3(B_ * S_), dim3(64), 0, stream>>>(ids, c_emb, c_smW, scal, xs);
  gemm_bt<false><<<dim3(3072 / 128, 2048 / 128), dim3(256), 0, stream>>>(xs, c_Wih, c_bih, (void*)xg, E_, 3072);
  // gru + piggybacked per-batch sort (WGs 64,65)
  gru_kernel<<<dim3(66), dim3(1024), 0, stream>>>(xg, c_Whh, c_bhh, hslot, states, ids, sorted);
  gemm_bt<true><<<dim3(512 / 128, 16), dim3(256), 0, stream>>>(states, c_Whe, c_bhe, (void*)hs, H_, 512);
  gemm_bt<true><<<dim3(256 / 128, 16), dim3(256), 0, stream>>>(states, c_Wq, c_bq, (void*)qb, H_, 256);
  gemm_bt<true><<<dim3(256 / 128, 16), dim3(256), 0, stream>>>(states, c_Wk, c_bk, (void*)kb, H_, 256);
  // scores[b] = q[b] @ k[b]^T (fp32, zero bias) via MFMA
  gemm_bt<false><<<dim3(S_ / 128, S_ / 128), dim3(256), 0, stream>>>(qb, kb, zbias, (void*)scores, M_, S_);
  gemm_bt<false><<<dim3(S_ / 128, S_ / 128), dim3(256), 0, stream>>>(qb + (size_t)S_ * M_, kb + (size_t)S_ * M_,
                                                                     zbias, (void*)(scores + (size_t)S_ * S_), M_, S_);
  gk_kernel<<<dim3(512), dim3(256), 0, stream>>>(states, c_Wg, c_bg, gws);
  // big V-GEMM first (transposed block mapping: grid (16, 250), B-panel reused in L2)
  gemm_v<<<dim3(16, V_ / 128), dim3(256), 0, stream>>>(hs, c_emb, c_ob, out, E_, V_);
  // fused attention+scatter adds gated contributions onto the final logits
  attn_scatter_kernel<<<dim3(S_, B_), dim3(256), 0, stream>>>(scores, gws, scal, sorted, out);
}